// Round 6
// baseline (430.453 us; speedup 1.0000x reference)
//
#include <hip/hip_runtime.h>
#include <hip/hip_bf16.h>
#include <hip/hip_fp16.h>
#include <math.h>

// ---------------------------------------------------------------------------
// GATv2 x2 + log_softmax + gated rule-net.
// R5: node_agg restructured as two scans (logit scan with fmax-only carried
// dep, spill logits to L2-resident scratch; then exp+accum scan with zero
// shuffles and independent iterations). Logit dot via packed-fp16 v_pk_* +
// v_dot2_f32_f16. Tables stay fp16, all accumulation fp32.
// ---------------------------------------------------------------------------

typedef _Float16 h2 __attribute__((ext_vector_type(2)));
union H2U { unsigned int u; h2 h; };
__device__ inline h2 bch2(unsigned int x) { H2U t; t.u = x; return t.h; }

__device__ inline void store_half4(__half* p, float a, float b, float c, float d) {
    __half2 h01 = __floats2half2_rn(a, b);
    __half2 h23 = __floats2half2_rn(c, d);
    uint2 u;
    u.x = *(unsigned int*)&h01;
    u.y = *(unsigned int*)&h23;
    *(uint2*)p = u;
}

__global__ void fill_int_kernel(int* __restrict__ p, int v, int count) {
    int i = blockIdx.x * blockDim.x + threadIdx.x;
    if (i < count) p[i] = v;
}

__global__ void hist_kernel(const int* __restrict__ ei, int* __restrict__ deg, int E) {
    int e = blockIdx.x * blockDim.x + threadIdx.x;
    if (e < E) atomicAdd(&deg[ei[E + e]], 1);
}

__global__ __launch_bounds__(1024)
void scan_block_kernel(const int* __restrict__ deg, int* __restrict__ rowptr,
                       int* __restrict__ partials, int n) {
    __shared__ int s[1024];
    int i = blockIdx.x * 1024 + threadIdx.x;
    int v = (i < n) ? deg[i] : 0;
    s[threadIdx.x] = v;
    __syncthreads();
    #pragma unroll
    for (int off = 1; off < 1024; off <<= 1) {
        int t = (threadIdx.x >= off) ? s[threadIdx.x - off] : 0;
        __syncthreads();
        s[threadIdx.x] += t;
        __syncthreads();
    }
    if (i < n) rowptr[i + 1] = s[threadIdx.x];
    if (threadIdx.x == 1023) partials[blockIdx.x] = s[1023];
}

__global__ __launch_bounds__(1024)
void scan_partials_kernel(int* __restrict__ partials, int nparts) {
    __shared__ int s[1024];
    int v = (threadIdx.x < nparts) ? partials[threadIdx.x] : 0;
    s[threadIdx.x] = v;
    __syncthreads();
    #pragma unroll
    for (int off = 1; off < 1024; off <<= 1) {
        int t = (threadIdx.x >= off) ? s[threadIdx.x - off] : 0;
        __syncthreads();
        s[threadIdx.x] += t;
        __syncthreads();
    }
    if (threadIdx.x < nparts) partials[threadIdx.x] = s[threadIdx.x] - v;  // exclusive
}

__global__ __launch_bounds__(1024)
void scan_apply_kernel(int* __restrict__ rowptr, const int* __restrict__ partials,
                       int* __restrict__ cursor, int n) {
    int i = blockIdx.x * 1024 + threadIdx.x;
    if (i == 0) { rowptr[0] = 0; cursor[0] = 0; }
    if (i < n) {
        int val = rowptr[i + 1] + partials[blockIdx.x];
        rowptr[i + 1] = val;
        if (i + 1 < n) cursor[i + 1] = val;
    }
}

__global__ void scatter_kernel(const int* __restrict__ ei, int* __restrict__ cursor,
                               int* __restrict__ srcs, int E, int ET) {
    int e = blockIdx.x * blockDim.x + threadIdx.x;
    if (e >= ET) return;
    int src, dst;
    if (e < E) { src = ei[e]; dst = ei[E + e]; }
    else       { src = dst = e - E; }
    int pos = atomicAdd(&cursor[dst], 1);
    srcs[pos] = src;
}

// Fused dual GEMM: Y0[n,M]=X@W0, Y1[n,M]=X@W1 (M=MTOT/2), K=128, fp16 output.
template<int MTOT>
__global__ __launch_bounds__(256)
void gemm_dual_kernel(const float* __restrict__ X,
                      const float* __restrict__ W0, const float* __restrict__ W1,
                      __half* __restrict__ Y0, __half* __restrict__ Y1, int n) {
    constexpr int K = 128, BK = 32, BM = 64;
    constexpr int M = MTOT / 2;
    constexpr int NJ = MTOT / 32;
    constexpr int NB = NJ / 4;
    __shared__ float sXT[BK][68];        // [k][row], transposed
    __shared__ float sW[BK][MTOT];
    int tid = threadIdx.x;
    int cc = tid & 31, rr = tid >> 5;
    int row0 = blockIdx.x * BM;
    float acc[8][NJ];
    #pragma unroll
    for (int i = 0; i < 8; i++)
        #pragma unroll
        for (int j = 0; j < NJ; j++) acc[i][j] = 0.f;

    for (int kc = 0; kc < K / BK; ++kc) {
        #pragma unroll
        for (int t = tid; t < BM * BK / 4; t += 256) {
            int r = t >> 3, c4 = t & 7;
            int grow = row0 + r;
            float4 v = (grow < n) ? *(const float4*)(X + (size_t)grow * K + kc * BK + c4 * 4)
                                  : make_float4(0.f, 0.f, 0.f, 0.f);
            sXT[c4 * 4 + 0][r] = v.x;
            sXT[c4 * 4 + 1][r] = v.y;
            sXT[c4 * 4 + 2][r] = v.z;
            sXT[c4 * 4 + 3][r] = v.w;
        }
        #pragma unroll
        for (int t = tid; t < BK * MTOT / 4; t += 256) {
            int kr = t / (MTOT / 4), m4 = t % (MTOT / 4);
            int m = m4 * 4, gk = kc * BK + kr;
            float4 v = (m < M) ? *(const float4*)(W0 + (size_t)gk * M + m)
                               : *(const float4*)(W1 + (size_t)gk * M + (m - M));
            *(float4*)(&sW[kr][m]) = v;
        }
        __syncthreads();
        #pragma unroll 8
        for (int k = 0; k < BK; ++k) {
            float4 a0 = *(const float4*)(&sXT[k][rr * 8]);
            float4 a1 = *(const float4*)(&sXT[k][rr * 8 + 4]);
            float a[8] = {a0.x, a0.y, a0.z, a0.w, a1.x, a1.y, a1.z, a1.w};
            float b[NJ];
            #pragma unroll
            for (int q = 0; q < NB; ++q) {
                float4 bv = *(const float4*)(&sW[k][q * 128 + cc * 4]);
                b[q * 4 + 0] = bv.x; b[q * 4 + 1] = bv.y;
                b[q * 4 + 2] = bv.z; b[q * 4 + 3] = bv.w;
            }
            #pragma unroll
            for (int i = 0; i < 8; i++)
                #pragma unroll
                for (int j = 0; j < NJ; j++) acc[i][j] += a[i] * b[j];
        }
        __syncthreads();
    }
    #pragma unroll
    for (int i = 0; i < 8; i++) {
        int row = row0 + rr * 8 + i;
        if (row >= n) continue;
        #pragma unroll
        for (int q = 0; q < NB; ++q) {
            int col = q * 128 + cc * 4;
            if (col < M)
                store_half4(Y0 + (size_t)row * M + col,
                            acc[i][q * 4], acc[i][q * 4 + 1], acc[i][q * 4 + 2], acc[i][q * 4 + 3]);
            else
                store_half4(Y1 + (size_t)row * M + (col - M),
                            acc[i][q * 4], acc[i][q * 4 + 1], acc[i][q * 4 + 2], acc[i][q * 4 + 3]);
        }
    }
}

// One 16-lane group per (node, head), two scans:
//  scan 1: per-edge logit via pk_add/pk_max + fdot2 (fp32 acc), butterfly
//          reduce, spill to lg[], track max with plain fmax (no exp chain).
//  scan 2: w = exp(lg[k]-m); acc += w*xl (no shuffles, independent iters).
template<int H, bool RELU_BIAS>
__global__ __launch_bounds__(256)
void node_agg_kernel(const __half* __restrict__ xl, const __half* __restrict__ xr,
                     const int* __restrict__ rowptr, const int* __restrict__ srcs,
                     float* __restrict__ lg,
                     const float* __restrict__ att, const float* __restrict__ bias,
                     float* __restrict__ out, int n) {
    int g = (blockIdx.x * blockDim.x + threadIdx.x) >> 4;
    int lane = threadIdx.x & 15;
    if (g >= n * H) return;
    int node = g / H, head = g % H;
    const int HC = H * 64;
    int cbase = head * 64 + lane * 4;
    uint2 ur = *(const uint2*)(xr + (size_t)node * HC + cbase);
    h2 r0 = bch2(ur.x), r1 = bch2(ur.y);
    float4 a4 = *(const float4*)(att + cbase);
    h2 a0 = {(_Float16)a4.x, (_Float16)a4.y};
    h2 a1 = {(_Float16)a4.z, (_Float16)a4.w};
    const h2 k02 = {(_Float16)0.2f, (_Float16)0.2f};
    int start = rowptr[node], end = rowptr[node + 1];

    // ---- scan 1: logits + max ----
    float m = -INFINITY;
    for (int k = start; k < end; ++k) {
        int src = srcs[k];
        uint2 u = *(const uint2*)(xl + (size_t)src * HC + cbase);
        h2 s0 = bch2(u.x) + r0;
        h2 s1 = bch2(u.y) + r1;
        s0 = __builtin_elementwise_max(s0, s0 * k02);   // leaky_relu (both signs)
        s1 = __builtin_elementwise_max(s1, s1 * k02);
        float p = __builtin_amdgcn_fdot2(s0, a0, 0.f, false);
        p = __builtin_amdgcn_fdot2(s1, a1, p, false);
        #pragma unroll
        for (int o = 8; o; o >>= 1) p += __shfl_xor(p, o, 16);
        if (lane == 0) lg[(size_t)k * H + head] = p;
        m = fmaxf(m, p);
    }

    // ---- scan 2: exp + weighted accumulation (no cross-lane ops) ----
    float d = 0.f;
    float4 acc = make_float4(0.f, 0.f, 0.f, 0.f);
    for (int k = start; k < end; ++k) {
        int src = srcs[k];
        float w = __expf(lg[(size_t)k * H + head] - m);
        uint2 u = *(const uint2*)(xl + (size_t)src * HC + cbase);
        h2 l0 = bch2(u.x), l1 = bch2(u.y);
        d += w;
        acc.x += w * (float)l0[0];
        acc.y += w * (float)l0[1];
        acc.z += w * (float)l1[0];
        acc.w += w * (float)l1[1];
    }
    float inv = 1.f / (d + 1e-16f);
    float4 o4 = make_float4(acc.x * inv, acc.y * inv, acc.z * inv, acc.w * inv);
    if (RELU_BIAS) {
        float4 b4 = *(const float4*)(bias + cbase);
        o4.x = fmaxf(o4.x + b4.x, 0.f);
        o4.y = fmaxf(o4.y + b4.y, 0.f);
        o4.z = fmaxf(o4.z + b4.z, 0.f);
        o4.w = fmaxf(o4.w + b4.w, 0.f);
    }
    *(float4*)(out + (size_t)node * HC + cbase) = o4;
}

// One wave per node: v2+bias -> log_softmax -> rule net -> out
__global__ __launch_bounds__(256)
void final_kernel(const float* __restrict__ v2, const float* __restrict__ b2,
                  const float* __restrict__ We1, const float* __restrict__ be1,
                  const float* __restrict__ We2, const float* __restrict__ be2,
                  float* __restrict__ out, int n) {
    __shared__ float sW1[64 * 64], sW2[64 * 64], sb1[64], sb2[64];
    __shared__ float srow[4][64], strow[4][64];
    for (int i = threadIdx.x; i < 64 * 64; i += 256) { sW1[i] = We1[i]; sW2[i] = We2[i]; }
    if (threadIdx.x < 64) { sb1[threadIdx.x] = be1[threadIdx.x]; sb2[threadIdx.x] = be2[threadIdx.x]; }
    __syncthreads();
    int wave = threadIdx.x >> 6, lane = threadIdx.x & 63;
    int node = blockIdx.x * 4 + wave;
    if (node >= n) return;
    float v = v2[(size_t)node * 64 + lane] + b2[lane];
    float m = v;
    #pragma unroll
    for (int o = 32; o; o >>= 1) m = fmaxf(m, __shfl_xor(m, o));
    float p = expf(v - m);
    float s = p;
    #pragma unroll
    for (int o = 32; o; o >>= 1) s += __shfl_xor(s, o);
    float ls = v - m - logf(s);
    srow[wave][lane] = ls;
    float acc = sb1[lane];
    #pragma unroll 8
    for (int k = 0; k < 64; k++) acc += srow[wave][k] * sW1[k * 64 + lane];
    float t = acc > 0.f ? acc : 0.f;
    strow[wave][lane] = t;
    acc = sb2[lane];
    #pragma unroll 8
    for (int k = 0; k < 64; k++) acc += strow[wave][k] * sW2[k * 64 + lane];
    float g = 1.f / (1.f + expf(-acc));
    out[(size_t)node * 64 + lane] = ls + g;
}

extern "C" void kernel_launch(void* const* d_in, const int* in_sizes, int n_in,
                              void* d_out, int out_size, void* d_ws, size_t ws_size,
                              hipStream_t stream) {
    const float* x    = (const float*)d_in[0];
    const int*   ei   = (const int*)d_in[1];
    const float* Wl1  = (const float*)d_in[2];
    const float* Wr1  = (const float*)d_in[3];
    const float* att1 = (const float*)d_in[4];
    const float* b1   = (const float*)d_in[5];
    const float* Wl2  = (const float*)d_in[6];
    const float* Wr2  = (const float*)d_in[7];
    const float* att2 = (const float*)d_in[8];
    const float* b2   = (const float*)d_in[9];
    const float* We1  = (const float*)d_in[10];
    const float* be1  = (const float*)d_in[11];
    const float* We2  = (const float*)d_in[12];
    const float* be2  = (const float*)d_in[13];
    float* out = (float*)d_out;

    const int n  = in_sizes[0] / 128;
    const int E  = in_sizes[1] / 2;
    const int ET = E + n;
    const int nchunks = (n + 1023) / 1024;

    float* ws = (float*)d_ws;
    size_t o = 0;
    __half* xl1 = (__half*)(ws + o); o += (size_t)n * 64;   // n*128 halves
    __half* xr1 = (__half*)(ws + o); o += (size_t)n * 64;   // n*128 halves
    float*  h1  = ws + o;            o += (size_t)n * 128;
    float*  v2  = ws + o;            o += (size_t)n * 64;
    float*  lg  = ws + o;            o += (size_t)ET * 2;   // logit scratch
    int* rowptr   = (int*)(ws + o); o += (size_t)(n + 1);
    int* cursor   = (int*)(ws + o); o += (size_t)n;
    int* srcs     = (int*)(ws + o); o += (size_t)ET;
    int* partials = (int*)(ws + o); o += 1024;
    // layer-2 fp16 tables reuse layer-1 table space (dead by then)
    __half* xl2 = xl1;
    __half* xr2 = xl1 + (size_t)n * 64;
    int* deg = cursor;  // deg reuses cursor pre-scan; cursor rebuilt by scan_apply

    const int BS = 256;
    auto blocks = [](long long t, int bs) { return (int)((t + bs - 1) / bs); };

    // ---- CSR build (by dst), self-loops via deg init = 1 ----
    fill_int_kernel<<<blocks(n, BS), BS, 0, stream>>>(deg, 1, n);
    hist_kernel<<<blocks(E, BS), BS, 0, stream>>>(ei, deg, E);
    scan_block_kernel<<<nchunks, 1024, 0, stream>>>(deg, rowptr, partials, n);
    scan_partials_kernel<<<1, 1024, 0, stream>>>(partials, nchunks);
    scan_apply_kernel<<<nchunks, 1024, 0, stream>>>(rowptr, partials, cursor, n);
    scatter_kernel<<<blocks(ET, BS), BS, 0, stream>>>(ei, cursor, srcs, E, ET);

    // ---- layer 1 ----
    gemm_dual_kernel<256><<<blocks(n, 64), BS, 0, stream>>>(x, Wl1, Wr1, xl1, xr1, n);
    node_agg_kernel<2, true><<<blocks((long long)n * 2 * 16, BS), BS, 0, stream>>>(
        xl1, xr1, rowptr, srcs, lg, att1, b1, h1, n);

    // ---- layer 2 ----
    gemm_dual_kernel<128><<<blocks(n, 64), BS, 0, stream>>>(h1, Wl2, Wr2, xl2, xr2, n);
    node_agg_kernel<1, false><<<blocks((long long)n * 16, BS), BS, 0, stream>>>(
        xl2, xr2, rowptr, srcs, lg, att2, nullptr, v2, n);

    // ---- finalize: bias + log_softmax + rule net ----
    final_kernel<<<blocks(((long long)n + 3) / 4 * 256, BS), BS, 0, stream>>>(
        v2, b2, We1, be1, We2, be2, out, n);
}

// Round 7
// 312.767 us; speedup vs baseline: 1.3763x; 1.3763x over previous
//
#include <hip/hip_runtime.h>
#include <hip/hip_bf16.h>
#include <hip/hip_fp16.h>
#include <math.h>

// ---------------------------------------------------------------------------
// GATv2 x2 + log_softmax + gated rule-net.
// R6: node_agg back to single-pass (R5 two-scan reverted). New structure:
// GROUP=4 lanes per (node,head) -> 16 groups/wave (4x concurrency), DPP
// quad-perm reduce (2 VALU ops, no ds_swizzle), exp without max-subtraction
// (logits are O(8); fp32 exp safe; kills the carried rescale chain).
// ---------------------------------------------------------------------------

typedef _Float16 h2 __attribute__((ext_vector_type(2)));
union H2U { unsigned int u; h2 h; };
__device__ inline h2 bch2(unsigned int x) { H2U t; t.u = x; return t.h; }

__device__ inline float dpp_xor1(float x) {
    int v = __builtin_amdgcn_mov_dpp(__builtin_bit_cast(int, x), 0xB1, 0xF, 0xF, true);
    return __builtin_bit_cast(float, v);
}
__device__ inline float dpp_xor2(float x) {
    int v = __builtin_amdgcn_mov_dpp(__builtin_bit_cast(int, x), 0x4E, 0xF, 0xF, true);
    return __builtin_bit_cast(float, v);
}

__device__ inline void store_half4(__half* p, float a, float b, float c, float d) {
    __half2 h01 = __floats2half2_rn(a, b);
    __half2 h23 = __floats2half2_rn(c, d);
    uint2 u;
    u.x = *(unsigned int*)&h01;
    u.y = *(unsigned int*)&h23;
    *(uint2*)p = u;
}

__global__ void fill_int_kernel(int* __restrict__ p, int v, int count) {
    int i = blockIdx.x * blockDim.x + threadIdx.x;
    if (i < count) p[i] = v;
}

__global__ void hist_kernel(const int* __restrict__ ei, int* __restrict__ deg, int E) {
    int e = blockIdx.x * blockDim.x + threadIdx.x;
    if (e < E) atomicAdd(&deg[ei[E + e]], 1);
}

__global__ __launch_bounds__(1024)
void scan_block_kernel(const int* __restrict__ deg, int* __restrict__ rowptr,
                       int* __restrict__ partials, int n) {
    __shared__ int s[1024];
    int i = blockIdx.x * 1024 + threadIdx.x;
    int v = (i < n) ? deg[i] : 0;
    s[threadIdx.x] = v;
    __syncthreads();
    #pragma unroll
    for (int off = 1; off < 1024; off <<= 1) {
        int t = (threadIdx.x >= off) ? s[threadIdx.x - off] : 0;
        __syncthreads();
        s[threadIdx.x] += t;
        __syncthreads();
    }
    if (i < n) rowptr[i + 1] = s[threadIdx.x];
    if (threadIdx.x == 1023) partials[blockIdx.x] = s[1023];
}

__global__ __launch_bounds__(1024)
void scan_partials_kernel(int* __restrict__ partials, int nparts) {
    __shared__ int s[1024];
    int v = (threadIdx.x < nparts) ? partials[threadIdx.x] : 0;
    s[threadIdx.x] = v;
    __syncthreads();
    #pragma unroll
    for (int off = 1; off < 1024; off <<= 1) {
        int t = (threadIdx.x >= off) ? s[threadIdx.x - off] : 0;
        __syncthreads();
        s[threadIdx.x] += t;
        __syncthreads();
    }
    if (threadIdx.x < nparts) partials[threadIdx.x] = s[threadIdx.x] - v;  // exclusive
}

__global__ __launch_bounds__(1024)
void scan_apply_kernel(int* __restrict__ rowptr, const int* __restrict__ partials,
                       int* __restrict__ cursor, int n) {
    int i = blockIdx.x * 1024 + threadIdx.x;
    if (i == 0) { rowptr[0] = 0; cursor[0] = 0; }
    if (i < n) {
        int val = rowptr[i + 1] + partials[blockIdx.x];
        rowptr[i + 1] = val;
        if (i + 1 < n) cursor[i + 1] = val;
    }
}

__global__ void scatter_kernel(const int* __restrict__ ei, int* __restrict__ cursor,
                               int* __restrict__ srcs, int E, int ET) {
    int e = blockIdx.x * blockDim.x + threadIdx.x;
    if (e >= ET) return;
    int src, dst;
    if (e < E) { src = ei[e]; dst = ei[E + e]; }
    else       { src = dst = e - E; }
    int pos = atomicAdd(&cursor[dst], 1);
    srcs[pos] = src;
}

// Fused dual GEMM: Y0[n,M]=X@W0, Y1[n,M]=X@W1 (M=MTOT/2), K=128, fp16 output.
template<int MTOT>
__global__ __launch_bounds__(256)
void gemm_dual_kernel(const float* __restrict__ X,
                      const float* __restrict__ W0, const float* __restrict__ W1,
                      __half* __restrict__ Y0, __half* __restrict__ Y1, int n) {
    constexpr int K = 128, BK = 32, BM = 64;
    constexpr int M = MTOT / 2;
    constexpr int NJ = MTOT / 32;
    constexpr int NB = NJ / 4;
    __shared__ float sXT[BK][68];        // [k][row], transposed
    __shared__ float sW[BK][MTOT];
    int tid = threadIdx.x;
    int cc = tid & 31, rr = tid >> 5;
    int row0 = blockIdx.x * BM;
    float acc[8][NJ];
    #pragma unroll
    for (int i = 0; i < 8; i++)
        #pragma unroll
        for (int j = 0; j < NJ; j++) acc[i][j] = 0.f;

    for (int kc = 0; kc < K / BK; ++kc) {
        #pragma unroll
        for (int t = tid; t < BM * BK / 4; t += 256) {
            int r = t >> 3, c4 = t & 7;
            int grow = row0 + r;
            float4 v = (grow < n) ? *(const float4*)(X + (size_t)grow * K + kc * BK + c4 * 4)
                                  : make_float4(0.f, 0.f, 0.f, 0.f);
            sXT[c4 * 4 + 0][r] = v.x;
            sXT[c4 * 4 + 1][r] = v.y;
            sXT[c4 * 4 + 2][r] = v.z;
            sXT[c4 * 4 + 3][r] = v.w;
        }
        #pragma unroll
        for (int t = tid; t < BK * MTOT / 4; t += 256) {
            int kr = t / (MTOT / 4), m4 = t % (MTOT / 4);
            int m = m4 * 4, gk = kc * BK + kr;
            float4 v = (m < M) ? *(const float4*)(W0 + (size_t)gk * M + m)
                               : *(const float4*)(W1 + (size_t)gk * M + (m - M));
            *(float4*)(&sW[kr][m]) = v;
        }
        __syncthreads();
        #pragma unroll 8
        for (int k = 0; k < BK; ++k) {
            float4 a0 = *(const float4*)(&sXT[k][rr * 8]);
            float4 a1 = *(const float4*)(&sXT[k][rr * 8 + 4]);
            float a[8] = {a0.x, a0.y, a0.z, a0.w, a1.x, a1.y, a1.z, a1.w};
            float b[NJ];
            #pragma unroll
            for (int q = 0; q < NB; ++q) {
                float4 bv = *(const float4*)(&sW[k][q * 128 + cc * 4]);
                b[q * 4 + 0] = bv.x; b[q * 4 + 1] = bv.y;
                b[q * 4 + 2] = bv.z; b[q * 4 + 3] = bv.w;
            }
            #pragma unroll
            for (int i = 0; i < 8; i++)
                #pragma unroll
                for (int j = 0; j < NJ; j++) acc[i][j] += a[i] * b[j];
        }
        __syncthreads();
    }
    #pragma unroll
    for (int i = 0; i < 8; i++) {
        int row = row0 + rr * 8 + i;
        if (row >= n) continue;
        #pragma unroll
        for (int q = 0; q < NB; ++q) {
            int col = q * 128 + cc * 4;
            if (col < M)
                store_half4(Y0 + (size_t)row * M + col,
                            acc[i][q * 4], acc[i][q * 4 + 1], acc[i][q * 4 + 2], acc[i][q * 4 + 3]);
            else
                store_half4(Y1 + (size_t)row * M + (col - M),
                            acc[i][q * 4], acc[i][q * 4 + 1], acc[i][q * 4 + 2], acc[i][q * 4 + 3]);
        }
    }
}

// 4 lanes per (node, head); lane owns 16 channels (2x uint4 fp16 loads).
// Single pass: w = exp(logit) directly (logits O(8), fp32-safe; ratio is
// mathematically identical to max-subtracted softmax). Carried deps: d and
// per-channel acc FMAs only. Reduce = 2 DPP quad-perm adds.
template<int H, bool RELU_BIAS>
__global__ __launch_bounds__(256)
void node_agg_kernel(const __half* __restrict__ xl, const __half* __restrict__ xr,
                     const int* __restrict__ rowptr, const int* __restrict__ srcs,
                     const float* __restrict__ att, const float* __restrict__ bias,
                     float* __restrict__ out, int n) {
    int g = (blockIdx.x * blockDim.x + threadIdx.x) >> 2;
    int lane = threadIdx.x & 3;
    if (g >= n * H) return;
    int node = g / H, head = g % H;
    const int HC = H * 64;
    int cbase = head * 64 + lane * 16;

    const __half* xrp = xr + (size_t)node * HC + cbase;
    uint4 ur0 = *(const uint4*)(xrp);
    uint4 ur1 = *(const uint4*)(xrp + 8);
    h2 r[8] = {bch2(ur0.x), bch2(ur0.y), bch2(ur0.z), bch2(ur0.w),
               bch2(ur1.x), bch2(ur1.y), bch2(ur1.z), bch2(ur1.w)};
    const float* ap = att + cbase;
    h2 a[8];
    #pragma unroll
    for (int j = 0; j < 8; j++)
        a[j] = h2{(_Float16)ap[2 * j], (_Float16)ap[2 * j + 1]};
    const h2 k02 = {(_Float16)0.2f, (_Float16)0.2f};

    int start = rowptr[node], end = rowptr[node + 1];
    float d = 0.f;
    float acc[16];
    #pragma unroll
    for (int j = 0; j < 16; j++) acc[j] = 0.f;

    #pragma unroll 2
    for (int k = start; k < end; ++k) {
        int src = srcs[k];
        const __half* xlp = xl + (size_t)src * HC + cbase;
        uint4 u0 = *(const uint4*)(xlp);
        uint4 u1 = *(const uint4*)(xlp + 8);
        h2 l[8] = {bch2(u0.x), bch2(u0.y), bch2(u0.z), bch2(u0.w),
                   bch2(u1.x), bch2(u1.y), bch2(u1.z), bch2(u1.w)};
        float pa = 0.f, pb = 0.f;
        #pragma unroll
        for (int j = 0; j < 4; j++) {
            h2 s = l[j] + r[j];
            s = __builtin_elementwise_max(s, s * k02);   // leaky_relu
            pa = __builtin_amdgcn_fdot2(s, a[j], pa, false);
        }
        #pragma unroll
        for (int j = 4; j < 8; j++) {
            h2 s = l[j] + r[j];
            s = __builtin_elementwise_max(s, s * k02);
            pb = __builtin_amdgcn_fdot2(s, a[j], pb, false);
        }
        float p = pa + pb;
        p += dpp_xor1(p);
        p += dpp_xor2(p);          // all 4 lanes now hold the full logit
        float w = __expf(p);
        d += w;
        #pragma unroll
        for (int j = 0; j < 8; j++) {
            acc[2 * j]     += w * (float)l[j][0];
            acc[2 * j + 1] += w * (float)l[j][1];
        }
    }

    float inv = 1.f / (d + 1e-16f);
    float o[16];
    #pragma unroll
    for (int j = 0; j < 16; j++) o[j] = acc[j] * inv;
    if (RELU_BIAS) {
        const float* bp = bias + cbase;
        #pragma unroll
        for (int j = 0; j < 16; j++) o[j] = fmaxf(o[j] + bp[j], 0.f);
    }
    float* op = out + (size_t)node * HC + cbase;
    #pragma unroll
    for (int q = 0; q < 4; q++)
        *(float4*)(op + q * 4) = make_float4(o[q * 4], o[q * 4 + 1], o[q * 4 + 2], o[q * 4 + 3]);
}

// One wave per node: v2+bias -> log_softmax -> rule net -> out
__global__ __launch_bounds__(256)
void final_kernel(const float* __restrict__ v2, const float* __restrict__ b2,
                  const float* __restrict__ We1, const float* __restrict__ be1,
                  const float* __restrict__ We2, const float* __restrict__ be2,
                  float* __restrict__ out, int n) {
    __shared__ float sW1[64 * 64], sW2[64 * 64], sb1[64], sb2[64];
    __shared__ float srow[4][64], strow[4][64];
    for (int i = threadIdx.x; i < 64 * 64; i += 256) { sW1[i] = We1[i]; sW2[i] = We2[i]; }
    if (threadIdx.x < 64) { sb1[threadIdx.x] = be1[threadIdx.x]; sb2[threadIdx.x] = be2[threadIdx.x]; }
    __syncthreads();
    int wave = threadIdx.x >> 6, lane = threadIdx.x & 63;
    int node = blockIdx.x * 4 + wave;
    if (node >= n) return;
    float v = v2[(size_t)node * 64 + lane] + b2[lane];
    float m = v;
    #pragma unroll
    for (int o = 32; o; o >>= 1) m = fmaxf(m, __shfl_xor(m, o));
    float p = expf(v - m);
    float s = p;
    #pragma unroll
    for (int o = 32; o; o >>= 1) s += __shfl_xor(s, o);
    float ls = v - m - logf(s);
    srow[wave][lane] = ls;
    float acc = sb1[lane];
    #pragma unroll 8
    for (int k = 0; k < 64; k++) acc += srow[wave][k] * sW1[k * 64 + lane];
    float t = acc > 0.f ? acc : 0.f;
    strow[wave][lane] = t;
    acc = sb2[lane];
    #pragma unroll 8
    for (int k = 0; k < 64; k++) acc += strow[wave][k] * sW2[k * 64 + lane];
    float g = 1.f / (1.f + expf(-acc));
    out[(size_t)node * 64 + lane] = ls + g;
}

extern "C" void kernel_launch(void* const* d_in, const int* in_sizes, int n_in,
                              void* d_out, int out_size, void* d_ws, size_t ws_size,
                              hipStream_t stream) {
    const float* x    = (const float*)d_in[0];
    const int*   ei   = (const int*)d_in[1];
    const float* Wl1  = (const float*)d_in[2];
    const float* Wr1  = (const float*)d_in[3];
    const float* att1 = (const float*)d_in[4];
    const float* b1   = (const float*)d_in[5];
    const float* Wl2  = (const float*)d_in[6];
    const float* Wr2  = (const float*)d_in[7];
    const float* att2 = (const float*)d_in[8];
    const float* b2   = (const float*)d_in[9];
    const float* We1  = (const float*)d_in[10];
    const float* be1  = (const float*)d_in[11];
    const float* We2  = (const float*)d_in[12];
    const float* be2  = (const float*)d_in[13];
    float* out = (float*)d_out;

    const int n  = in_sizes[0] / 128;
    const int E  = in_sizes[1] / 2;
    const int ET = E + n;
    const int nchunks = (n + 1023) / 1024;

    float* ws = (float*)d_ws;
    size_t o = 0;
    __half* xl1 = (__half*)(ws + o); o += (size_t)n * 64;   // n*128 halves
    __half* xr1 = (__half*)(ws + o); o += (size_t)n * 64;   // n*128 halves
    float*  h1  = ws + o;            o += (size_t)n * 128;
    float*  v2  = ws + o;            o += (size_t)n * 64;
    int* rowptr   = (int*)(ws + o); o += (size_t)(n + 1);
    int* cursor   = (int*)(ws + o); o += (size_t)n;
    int* srcs     = (int*)(ws + o); o += (size_t)ET;
    int* partials = (int*)(ws + o); o += 1024;
    // layer-2 fp16 tables reuse layer-1 table space (dead by then)
    __half* xl2 = xl1;
    __half* xr2 = xl1 + (size_t)n * 64;
    int* deg = cursor;  // deg reuses cursor pre-scan; cursor rebuilt by scan_apply

    const int BS = 256;
    auto blocks = [](long long t, int bs) { return (int)((t + bs - 1) / bs); };

    // ---- CSR build (by dst), self-loops via deg init = 1 ----
    fill_int_kernel<<<blocks(n, BS), BS, 0, stream>>>(deg, 1, n);
    hist_kernel<<<blocks(E, BS), BS, 0, stream>>>(ei, deg, E);
    scan_block_kernel<<<nchunks, 1024, 0, stream>>>(deg, rowptr, partials, n);
    scan_partials_kernel<<<1, 1024, 0, stream>>>(partials, nchunks);
    scan_apply_kernel<<<nchunks, 1024, 0, stream>>>(rowptr, partials, cursor, n);
    scatter_kernel<<<blocks(ET, BS), BS, 0, stream>>>(ei, cursor, srcs, E, ET);

    // ---- layer 1 ----
    gemm_dual_kernel<256><<<blocks(n, 64), BS, 0, stream>>>(x, Wl1, Wr1, xl1, xr1, n);
    node_agg_kernel<2, true><<<blocks((long long)n * 2 * 4, BS), BS, 0, stream>>>(
        xl1, xr1, rowptr, srcs, att1, b1, h1, n);

    // ---- layer 2 ----
    gemm_dual_kernel<128><<<blocks(n, 64), BS, 0, stream>>>(h1, Wl2, Wr2, xl2, xr2, n);
    node_agg_kernel<1, false><<<blocks((long long)n * 4, BS), BS, 0, stream>>>(
        xl2, xr2, rowptr, srcs, att2, nullptr, v2, n);

    // ---- finalize: bias + log_softmax + rule net ----
    final_kernel<<<blocks(((long long)n + 3) / 4 * 256, BS), BS, 0, stream>>>(
        v2, b2, We1, be1, We2, be2, out, n);
}

// Round 8
// 279.573 us; speedup vs baseline: 1.5397x; 1.1187x over previous
//
#include <hip/hip_runtime.h>
#include <hip/hip_bf16.h>
#include <hip/hip_fp16.h>
#include <math.h>

// ---------------------------------------------------------------------------
// GATv2 x2 + log_softmax + gated rule-net.
// R7: GEMMs moved to MFMA (16x16x32 f16, fp32 accum). No LDS: A-frags direct
// from global (L2-resident), W pre-packed into B-frag layout once. node_agg
// layer-1 emits h1 as fp16 (only consumer is GEMM2). node_agg structure from
// R6 (4-lane groups, DPP reduce, no-max exp) unchanged.
// ---------------------------------------------------------------------------

typedef _Float16 h2 __attribute__((ext_vector_type(2)));
typedef _Float16 half8_t __attribute__((ext_vector_type(8)));
typedef float f32x4_t __attribute__((ext_vector_type(4)));
union H2U { unsigned int u; h2 h; };
__device__ inline h2 bch2(unsigned int x) { H2U t; t.u = x; return t.h; }

__device__ inline float dpp_xor1(float x) {
    int v = __builtin_amdgcn_mov_dpp(__builtin_bit_cast(int, x), 0xB1, 0xF, 0xF, true);
    return __builtin_bit_cast(float, v);
}
__device__ inline float dpp_xor2(float x) {
    int v = __builtin_amdgcn_mov_dpp(__builtin_bit_cast(int, x), 0x4E, 0xF, 0xF, true);
    return __builtin_bit_cast(float, v);
}

__global__ void fill_int_kernel(int* __restrict__ p, int v, int count) {
    int i = blockIdx.x * blockDim.x + threadIdx.x;
    if (i < count) p[i] = v;
}

__global__ void hist_kernel(const int* __restrict__ ei, int* __restrict__ deg, int E) {
    int e = blockIdx.x * blockDim.x + threadIdx.x;
    if (e < E) atomicAdd(&deg[ei[E + e]], 1);
}

__global__ __launch_bounds__(1024)
void scan_block_kernel(const int* __restrict__ deg, int* __restrict__ rowptr,
                       int* __restrict__ partials, int n) {
    __shared__ int s[1024];
    int i = blockIdx.x * 1024 + threadIdx.x;
    int v = (i < n) ? deg[i] : 0;
    s[threadIdx.x] = v;
    __syncthreads();
    #pragma unroll
    for (int off = 1; off < 1024; off <<= 1) {
        int t = (threadIdx.x >= off) ? s[threadIdx.x - off] : 0;
        __syncthreads();
        s[threadIdx.x] += t;
        __syncthreads();
    }
    if (i < n) rowptr[i + 1] = s[threadIdx.x];
    if (threadIdx.x == 1023) partials[blockIdx.x] = s[1023];
}

__global__ __launch_bounds__(1024)
void scan_partials_kernel(int* __restrict__ partials, int nparts) {
    __shared__ int s[1024];
    int v = (threadIdx.x < nparts) ? partials[threadIdx.x] : 0;
    s[threadIdx.x] = v;
    __syncthreads();
    #pragma unroll
    for (int off = 1; off < 1024; off <<= 1) {
        int t = (threadIdx.x >= off) ? s[threadIdx.x - off] : 0;
        __syncthreads();
        s[threadIdx.x] += t;
        __syncthreads();
    }
    if (threadIdx.x < nparts) partials[threadIdx.x] = s[threadIdx.x] - v;  // exclusive
}

__global__ __launch_bounds__(1024)
void scan_apply_kernel(int* __restrict__ rowptr, const int* __restrict__ partials,
                       int* __restrict__ cursor, int n) {
    int i = blockIdx.x * 1024 + threadIdx.x;
    if (i == 0) { rowptr[0] = 0; cursor[0] = 0; }
    if (i < n) {
        int val = rowptr[i + 1] + partials[blockIdx.x];
        rowptr[i + 1] = val;
        if (i + 1 < n) cursor[i + 1] = val;
    }
}

__global__ void scatter_kernel(const int* __restrict__ ei, int* __restrict__ cursor,
                               int* __restrict__ srcs, int E, int ET) {
    int e = blockIdx.x * blockDim.x + threadIdx.x;
    if (e >= ET) return;
    int src, dst;
    if (e < E) { src = ei[e]; dst = ei[E + e]; }
    else       { src = dst = e - E; }
    int pos = atomicAdd(&cursor[dst], 1);
    srcs[pos] = src;
}

// fp32 -> fp16 convert (4 floats / thread)
__global__ void f2h_kernel(const float* __restrict__ in, __half* __restrict__ out,
                           long long count4) {
    long long i = (long long)blockIdx.x * blockDim.x + threadIdx.x;
    if (i >= count4) return;
    float4 v = *(const float4*)(in + i * 4);
    __half2 h01 = __floats2half2_rn(v.x, v.y);
    __half2 h23 = __floats2half2_rn(v.z, v.w);
    uint2 u;
    u.x = *(unsigned int*)&h01;
    u.y = *(unsigned int*)&h23;
    *(uint2*)(out + i * 4) = u;
}

// Pack [W0|W1] (each [128][NC/2] fp32) into MFMA B-frag layout:
// Wp[((t*4 + c)*64 + lane)*8 + e] = Wcat[c*32 + (lane>>4)*8 + e][t*16 + (lane&15)]
template<int NC>
__global__ void pack_w_kernel(const float* __restrict__ W0, const float* __restrict__ W1,
                              __half* __restrict__ Wp) {
    constexpr int M = NC / 2;
    int idx = blockIdx.x * 256 + threadIdx.x;
    if (idx >= (NC / 16) * 4 * 64) return;
    int lane = idx & 63, c = (idx >> 6) & 3, t = idx >> 8;
    int col = t * 16 + (lane & 15);
    int k0 = c * 32 + (lane >> 4) * 8;
    __half tmp[8];
    #pragma unroll
    for (int e = 0; e < 8; e++) {
        int k = k0 + e;
        float v = (col < M) ? W0[(size_t)k * M + col] : W1[(size_t)k * M + (col - M)];
        tmp[e] = __float2half(v);
    }
    *(uint4*)(Wp + (size_t)idx * 8) = *(uint4*)tmp;
}

// MFMA dual GEMM: Y0|Y1 [n, NC/2 each] fp16 = A[n,128] fp16 @ Wp (packed).
// One wave per (16-row tile, col quarter); no LDS; A-frags from global.
template<int NC>
__global__ __launch_bounds__(256)
void gemm_mfma_kernel(const __half* __restrict__ A, const __half* __restrict__ Wp,
                      __half* __restrict__ Y0, __half* __restrict__ Y1, int n) {
    constexpr int KC = 4;              // k-chunks of 32 (K=128)
    constexpr int NT = NC / 16;        // col tiles
    constexpr int NTW = NT / 4;        // col tiles per wave
    constexpr int M = NC / 2;
    int gw = (int)((blockIdx.x * 256 + threadIdx.x) >> 6);
    int lane = threadIdx.x & 63;
    int rt = gw >> 2;
    int wq = gw & 3;
    int row0 = rt * 16;
    if (row0 >= n) return;
    int arow = row0 + (lane & 15);
    int koff = (lane >> 4) * 8;
    half8_t af[KC];
    #pragma unroll
    for (int c = 0; c < KC; c++) {
        af[c] = (arow < n) ? *(const half8_t*)(A + (size_t)arow * 128 + c * 32 + koff)
                           : half8_t{0, 0, 0, 0, 0, 0, 0, 0};
    }
    #pragma unroll
    for (int t4 = 0; t4 < NTW; t4++) {
        int t = wq * NTW + t4;
        f32x4_t acc = {0.f, 0.f, 0.f, 0.f};
        #pragma unroll
        for (int c = 0; c < KC; c++) {
            half8_t bf = *(const half8_t*)(Wp + (((size_t)t * KC + c) * 64 + lane) * 8);
            acc = __builtin_amdgcn_mfma_f32_16x16x32_f16(af[c], bf, acc, 0, 0, 0);
        }
        int col = t * 16 + (lane & 15);
        #pragma unroll
        for (int r = 0; r < 4; r++) {
            int row = row0 + (lane >> 4) * 4 + r;
            if (row < n) {
                __half v = __float2half(acc[r]);
                if (col < M) Y0[(size_t)row * M + col] = v;
                else         Y1[(size_t)row * M + (col - M)] = v;
            }
        }
    }
}

// 4 lanes per (node, head); lane owns 16 channels. Single-pass, DPP reduce,
// exp without max-subtraction. RELU_BIAS=true -> fp16 out (h1), else fp32.
template<int H, bool RELU_BIAS>
__global__ __launch_bounds__(256)
void node_agg_kernel(const __half* __restrict__ xl, const __half* __restrict__ xr,
                     const int* __restrict__ rowptr, const int* __restrict__ srcs,
                     const float* __restrict__ att, const float* __restrict__ bias,
                     __half* __restrict__ outh, float* __restrict__ outf, int n) {
    int g = (blockIdx.x * blockDim.x + threadIdx.x) >> 2;
    int lane = threadIdx.x & 3;
    if (g >= n * H) return;
    int node = g / H, head = g % H;
    const int HC = H * 64;
    int cbase = head * 64 + lane * 16;

    const __half* xrp = xr + (size_t)node * HC + cbase;
    uint4 ur0 = *(const uint4*)(xrp);
    uint4 ur1 = *(const uint4*)(xrp + 8);
    h2 r[8] = {bch2(ur0.x), bch2(ur0.y), bch2(ur0.z), bch2(ur0.w),
               bch2(ur1.x), bch2(ur1.y), bch2(ur1.z), bch2(ur1.w)};
    const float* ap = att + cbase;
    h2 a[8];
    #pragma unroll
    for (int j = 0; j < 8; j++)
        a[j] = h2{(_Float16)ap[2 * j], (_Float16)ap[2 * j + 1]};
    const h2 k02 = {(_Float16)0.2f, (_Float16)0.2f};

    int start = rowptr[node], end = rowptr[node + 1];
    float d = 0.f;
    float acc[16];
    #pragma unroll
    for (int j = 0; j < 16; j++) acc[j] = 0.f;

    #pragma unroll 2
    for (int k = start; k < end; ++k) {
        int src = srcs[k];
        const __half* xlp = xl + (size_t)src * HC + cbase;
        uint4 u0 = *(const uint4*)(xlp);
        uint4 u1 = *(const uint4*)(xlp + 8);
        h2 l[8] = {bch2(u0.x), bch2(u0.y), bch2(u0.z), bch2(u0.w),
                   bch2(u1.x), bch2(u1.y), bch2(u1.z), bch2(u1.w)};
        float pa = 0.f, pb = 0.f;
        #pragma unroll
        for (int j = 0; j < 4; j++) {
            h2 s = l[j] + r[j];
            s = __builtin_elementwise_max(s, s * k02);   // leaky_relu
            pa = __builtin_amdgcn_fdot2(s, a[j], pa, false);
        }
        #pragma unroll
        for (int j = 4; j < 8; j++) {
            h2 s = l[j] + r[j];
            s = __builtin_elementwise_max(s, s * k02);
            pb = __builtin_amdgcn_fdot2(s, a[j], pb, false);
        }
        float p = pa + pb;
        p += dpp_xor1(p);
        p += dpp_xor2(p);          // all 4 lanes hold the full logit
        float w = __expf(p);
        d += w;
        #pragma unroll
        for (int j = 0; j < 8; j++) {
            acc[2 * j]     += w * (float)l[j][0];
            acc[2 * j + 1] += w * (float)l[j][1];
        }
    }

    float inv = 1.f / (d + 1e-16f);
    float o[16];
    #pragma unroll
    for (int j = 0; j < 16; j++) o[j] = acc[j] * inv;
    if (RELU_BIAS) {
        const float* bp = bias + cbase;
        #pragma unroll
        for (int j = 0; j < 16; j++) o[j] = fmaxf(o[j] + bp[j], 0.f);
        // pack 16 fp16 -> 2x uint4
        __half* op = outh + (size_t)node * HC + cbase;
        uint4 w0, w1;
        __half2 t0 = __floats2half2_rn(o[0], o[1]),  t1 = __floats2half2_rn(o[2], o[3]);
        __half2 t2 = __floats2half2_rn(o[4], o[5]),  t3 = __floats2half2_rn(o[6], o[7]);
        __half2 t4 = __floats2half2_rn(o[8], o[9]),  t5 = __floats2half2_rn(o[10], o[11]);
        __half2 t6 = __floats2half2_rn(o[12], o[13]), t7 = __floats2half2_rn(o[14], o[15]);
        w0.x = *(unsigned int*)&t0; w0.y = *(unsigned int*)&t1;
        w0.z = *(unsigned int*)&t2; w0.w = *(unsigned int*)&t3;
        w1.x = *(unsigned int*)&t4; w1.y = *(unsigned int*)&t5;
        w1.z = *(unsigned int*)&t6; w1.w = *(unsigned int*)&t7;
        *(uint4*)(op) = w0;
        *(uint4*)(op + 8) = w1;
    } else {
        float* op = outf + (size_t)node * HC + cbase;
        #pragma unroll
        for (int q = 0; q < 4; q++)
            *(float4*)(op + q * 4) = make_float4(o[q * 4], o[q * 4 + 1], o[q * 4 + 2], o[q * 4 + 3]);
    }
}

// One wave per node: v2+bias -> log_softmax -> rule net -> out
__global__ __launch_bounds__(256)
void final_kernel(const float* __restrict__ v2, const float* __restrict__ b2,
                  const float* __restrict__ We1, const float* __restrict__ be1,
                  const float* __restrict__ We2, const float* __restrict__ be2,
                  float* __restrict__ out, int n) {
    __shared__ float sW1[64 * 64], sW2[64 * 64], sb1[64], sb2[64];
    __shared__ float srow[4][64], strow[4][64];
    for (int i = threadIdx.x; i < 64 * 64; i += 256) { sW1[i] = We1[i]; sW2[i] = We2[i]; }
    if (threadIdx.x < 64) { sb1[threadIdx.x] = be1[threadIdx.x]; sb2[threadIdx.x] = be2[threadIdx.x]; }
    __syncthreads();
    int wave = threadIdx.x >> 6, lane = threadIdx.x & 63;
    int node = blockIdx.x * 4 + wave;
    if (node >= n) return;
    float v = v2[(size_t)node * 64 + lane] + b2[lane];
    float m = v;
    #pragma unroll
    for (int o = 32; o; o >>= 1) m = fmaxf(m, __shfl_xor(m, o));
    float p = expf(v - m);
    float s = p;
    #pragma unroll
    for (int o = 32; o; o >>= 1) s += __shfl_xor(s, o);
    float ls = v - m - logf(s);
    srow[wave][lane] = ls;
    float acc = sb1[lane];
    #pragma unroll 8
    for (int k = 0; k < 64; k++) acc += srow[wave][k] * sW1[k * 64 + lane];
    float t = acc > 0.f ? acc : 0.f;
    strow[wave][lane] = t;
    acc = sb2[lane];
    #pragma unroll 8
    for (int k = 0; k < 64; k++) acc += strow[wave][k] * sW2[k * 64 + lane];
    float g = 1.f / (1.f + expf(-acc));
    out[(size_t)node * 64 + lane] = ls + g;
}

extern "C" void kernel_launch(void* const* d_in, const int* in_sizes, int n_in,
                              void* d_out, int out_size, void* d_ws, size_t ws_size,
                              hipStream_t stream) {
    const float* x    = (const float*)d_in[0];
    const int*   ei   = (const int*)d_in[1];
    const float* Wl1  = (const float*)d_in[2];
    const float* Wr1  = (const float*)d_in[3];
    const float* att1 = (const float*)d_in[4];
    const float* b1   = (const float*)d_in[5];
    const float* Wl2  = (const float*)d_in[6];
    const float* Wr2  = (const float*)d_in[7];
    const float* att2 = (const float*)d_in[8];
    const float* b2   = (const float*)d_in[9];
    const float* We1  = (const float*)d_in[10];
    const float* be1  = (const float*)d_in[11];
    const float* We2  = (const float*)d_in[12];
    const float* be2  = (const float*)d_in[13];
    float* out = (float*)d_out;

    const int n  = in_sizes[0] / 128;
    const int E  = in_sizes[1] / 2;
    const int ET = E + n;
    const int nchunks = (n + 1023) / 1024;

    float* ws = (float*)d_ws;
    size_t o = 0;
    __half* xl1 = (__half*)(ws + o); o += (size_t)n * 64;   // [n,128] fp16
    __half* xr1 = (__half*)(ws + o); o += (size_t)n * 64;   // [n,128] fp16
    __half* xh  = (__half*)(ws + o); o += (size_t)n * 64;   // x as fp16 [n,128]
    __half* h1h = (__half*)(ws + o); o += (size_t)n * 64;   // h1 fp16 [n,128]
    float*  v2  = ws + o;            o += (size_t)n * 64;   // fp32 [n,64]
    __half* Wp1 = (__half*)(ws + o); o += 16384;            // 32768 halves
    __half* Wp2 = (__half*)(ws + o); o += 8192;             // 16384 halves
    int* rowptr   = (int*)(ws + o); o += (size_t)(n + 1);
    int* cursor   = (int*)(ws + o); o += (size_t)n;
    int* srcs     = (int*)(ws + o); o += (size_t)ET;
    int* partials = (int*)(ws + o); o += 1024;
    __half* xl2 = xl1;                     // [n,64] fp16 (reuses dead xl1 region)
    __half* xr2 = xl1 + (size_t)n * 64;
    int* deg = cursor;

    const int BS = 256;
    auto blocks = [](long long t, int bs) { return (int)((t + bs - 1) / bs); };

    // ---- CSR build (by dst), self-loops via deg init = 1 ----
    fill_int_kernel<<<blocks(n, BS), BS, 0, stream>>>(deg, 1, n);
    hist_kernel<<<blocks(E, BS), BS, 0, stream>>>(ei, deg, E);
    scan_block_kernel<<<nchunks, 1024, 0, stream>>>(deg, rowptr, partials, n);
    scan_partials_kernel<<<1, 1024, 0, stream>>>(partials, nchunks);
    scan_apply_kernel<<<nchunks, 1024, 0, stream>>>(rowptr, partials, cursor, n);
    scatter_kernel<<<blocks(ET, BS), BS, 0, stream>>>(ei, cursor, srcs, E, ET);

    // ---- one-time conversions / packs ----
    f2h_kernel<<<blocks((long long)n * 32, BS), BS, 0, stream>>>(x, xh, (long long)n * 32);
    pack_w_kernel<256><<<16, 256, 0, stream>>>(Wl1, Wr1, Wp1);
    pack_w_kernel<128><<<8, 256, 0, stream>>>(Wl2, Wr2, Wp2);

    // ---- layer 1 ----
    const int rt = (n + 15) / 16;          // row tiles
    gemm_mfma_kernel<256><<<rt, 256, 0, stream>>>(xh, Wp1, xl1, xr1, n);
    node_agg_kernel<2, true><<<blocks((long long)n * 2 * 4, BS), BS, 0, stream>>>(
        xl1, xr1, rowptr, srcs, att1, b1, h1h, nullptr, n);

    // ---- layer 2 ----
    gemm_mfma_kernel<128><<<rt, 256, 0, stream>>>(h1h, Wp2, xl2, xr2, n);
    node_agg_kernel<1, false><<<blocks((long long)n * 4, BS), BS, 0, stream>>>(
        xl2, xr2, rowptr, srcs, att2, nullptr, nullptr, v2, n);

    // ---- finalize: bias + log_softmax + rule net ----
    final_kernel<<<blocks(((long long)n + 3) / 4 * 256, BS), BS, 0, stream>>>(
        v2, b2, We1, be1, We2, be2, out, n);
}

// Round 9
// 248.989 us; speedup vs baseline: 1.7288x; 1.1228x over previous
//
#include <hip/hip_runtime.h>
#include <hip/hip_bf16.h>
#include <hip/hip_fp16.h>
#include <math.h>

// ---------------------------------------------------------------------------
// GATv2 x2 + log_softmax + gated rule-net.
// R8: (a) final_kernel split into ls_kernel + MFMA gate_kernel (rule-net was
// a scalar LDS-read-bound GEMM, 64us); (b) CSR atomic counters padded to
// 128B/counter to break TCC same-line atomic serialization (scatter 64us,
// VALUBusy 0.4% -> pure atomic contention).
// ---------------------------------------------------------------------------

typedef _Float16 h2 __attribute__((ext_vector_type(2)));
typedef _Float16 half8_t __attribute__((ext_vector_type(8)));
typedef float f32x4_t __attribute__((ext_vector_type(4)));
union H2U { unsigned int u; h2 h; };
__device__ inline h2 bch2(unsigned int x) { H2U t; t.u = x; return t.h; }

constexpr int CSTR = 32;   // counter stride in ints (128 B)

__device__ inline float dpp_xor1(float x) {
    int v = __builtin_amdgcn_mov_dpp(__builtin_bit_cast(int, x), 0xB1, 0xF, 0xF, true);
    return __builtin_bit_cast(float, v);
}
__device__ inline float dpp_xor2(float x) {
    int v = __builtin_amdgcn_mov_dpp(__builtin_bit_cast(int, x), 0x4E, 0xF, 0xF, true);
    return __builtin_bit_cast(float, v);
}

__global__ void fill_strided_kernel(int* __restrict__ p, int v, int count) {
    int i = blockIdx.x * blockDim.x + threadIdx.x;
    if (i < count) p[(size_t)i * CSTR] = v;
}

__global__ void hist_kernel(const int* __restrict__ ei, int* __restrict__ deg, int E) {
    int e = blockIdx.x * blockDim.x + threadIdx.x;
    if (e < E) atomicAdd(&deg[(size_t)ei[E + e] * CSTR], 1);
}

__global__ __launch_bounds__(1024)
void scan_block_kernel(const int* __restrict__ deg, int* __restrict__ rowptr,
                       int* __restrict__ partials, int n) {
    __shared__ int s[1024];
    int i = blockIdx.x * 1024 + threadIdx.x;
    int v = (i < n) ? deg[(size_t)i * CSTR] : 0;
    s[threadIdx.x] = v;
    __syncthreads();
    #pragma unroll
    for (int off = 1; off < 1024; off <<= 1) {
        int t = (threadIdx.x >= off) ? s[threadIdx.x - off] : 0;
        __syncthreads();
        s[threadIdx.x] += t;
        __syncthreads();
    }
    if (i < n) rowptr[i + 1] = s[threadIdx.x];
    if (threadIdx.x == 1023) partials[blockIdx.x] = s[1023];
}

__global__ __launch_bounds__(1024)
void scan_partials_kernel(int* __restrict__ partials, int nparts) {
    __shared__ int s[1024];
    int v = (threadIdx.x < nparts) ? partials[threadIdx.x] : 0;
    s[threadIdx.x] = v;
    __syncthreads();
    #pragma unroll
    for (int off = 1; off < 1024; off <<= 1) {
        int t = (threadIdx.x >= off) ? s[threadIdx.x - off] : 0;
        __syncthreads();
        s[threadIdx.x] += t;
        __syncthreads();
    }
    if (threadIdx.x < nparts) partials[threadIdx.x] = s[threadIdx.x] - v;  // exclusive
}

__global__ __launch_bounds__(1024)
void scan_apply_kernel(int* __restrict__ rowptr, const int* __restrict__ partials,
                       int* __restrict__ cursor, int n) {
    int i = blockIdx.x * 1024 + threadIdx.x;
    if (i == 0) { rowptr[0] = 0; cursor[0] = 0; }
    if (i < n) {
        int val = rowptr[i + 1] + partials[blockIdx.x];
        rowptr[i + 1] = val;
        if (i + 1 < n) cursor[(size_t)(i + 1) * CSTR] = val;
    }
}

__global__ void scatter_kernel(const int* __restrict__ ei, int* __restrict__ cursor,
                               int* __restrict__ srcs, int E, int ET) {
    int e = blockIdx.x * blockDim.x + threadIdx.x;
    if (e >= ET) return;
    int src, dst;
    if (e < E) { src = ei[e]; dst = ei[E + e]; }
    else       { src = dst = e - E; }
    int pos = atomicAdd(&cursor[(size_t)dst * CSTR], 1);
    srcs[pos] = src;
}

// fp32 -> fp16 convert (4 floats / thread)
__global__ void f2h_kernel(const float* __restrict__ in, __half* __restrict__ out,
                           long long count4) {
    long long i = (long long)blockIdx.x * blockDim.x + threadIdx.x;
    if (i >= count4) return;
    float4 v = *(const float4*)(in + i * 4);
    __half2 h01 = __floats2half2_rn(v.x, v.y);
    __half2 h23 = __floats2half2_rn(v.z, v.w);
    uint2 u;
    u.x = *(unsigned int*)&h01;
    u.y = *(unsigned int*)&h23;
    *(uint2*)(out + i * 4) = u;
}

// Pack weights into MFMA B-frag layout (16x16x32 f16):
// Wp[((t*KC + c)*64 + lane)*8 + e] = Wcat[c*32 + (lane>>4)*8 + e][t*16 + (lane&15)]
template<int NC, int K, bool DUAL>
__global__ void pack_w_kernel(const float* __restrict__ W0, const float* __restrict__ W1,
                              __half* __restrict__ Wp) {
    constexpr int KC = K / 32;
    constexpr int M = DUAL ? NC / 2 : NC;
    int idx = blockIdx.x * 256 + threadIdx.x;
    if (idx >= (NC / 16) * KC * 64) return;
    int lane = idx & 63;
    int c = (idx >> 6) % KC;
    int t = idx / (64 * KC);
    int col = t * 16 + (lane & 15);
    int k0 = c * 32 + (lane >> 4) * 8;
    __half tmp[8];
    #pragma unroll
    for (int e = 0; e < 8; e++) {
        int k = k0 + e;
        float v;
        if (DUAL) v = (col < M) ? W0[(size_t)k * M + col] : W1[(size_t)k * M + (col - M)];
        else      v = W0[(size_t)k * M + col];
        tmp[e] = __float2half(v);
    }
    *(uint4*)(Wp + (size_t)idx * 8) = *(uint4*)tmp;
}

// MFMA dual GEMM: Y0|Y1 [n, NC/2 each] fp16 = A[n,K] fp16 @ Wp (packed).
// One wave per (16-row tile, col quarter); no LDS; A-frags from global.
template<int NC, int K>
__global__ __launch_bounds__(256)
void gemm_mfma_kernel(const __half* __restrict__ A, const __half* __restrict__ Wp,
                      __half* __restrict__ Y0, __half* __restrict__ Y1, int n) {
    constexpr int KC = K / 32;
    constexpr int NT = NC / 16;
    constexpr int NTW = NT / 4;
    constexpr int M = NC / 2;
    int gw = (int)((blockIdx.x * 256 + threadIdx.x) >> 6);
    int lane = threadIdx.x & 63;
    int rt = gw >> 2;
    int wq = gw & 3;
    int row0 = rt * 16;
    if (row0 >= n) return;
    int arow = row0 + (lane & 15);
    int koff = (lane >> 4) * 8;
    half8_t af[KC];
    #pragma unroll
    for (int c = 0; c < KC; c++) {
        af[c] = (arow < n) ? *(const half8_t*)(A + (size_t)arow * K + c * 32 + koff)
                           : half8_t{0, 0, 0, 0, 0, 0, 0, 0};
    }
    #pragma unroll
    for (int t4 = 0; t4 < NTW; t4++) {
        int t = wq * NTW + t4;
        f32x4_t acc = {0.f, 0.f, 0.f, 0.f};
        #pragma unroll
        for (int c = 0; c < KC; c++) {
            half8_t bf = *(const half8_t*)(Wp + (((size_t)t * KC + c) * 64 + lane) * 8);
            acc = __builtin_amdgcn_mfma_f32_16x16x32_f16(af[c], bf, acc, 0, 0, 0);
        }
        int col = t * 16 + (lane & 15);
        #pragma unroll
        for (int r = 0; r < 4; r++) {
            int row = row0 + (lane >> 4) * 4 + r;
            if (row < n) {
                __half v = __float2half(acc[r]);
                if (col < M) Y0[(size_t)row * M + col] = v;
                else         Y1[(size_t)row * M + (col - M)] = v;
            }
        }
    }
}

// 4 lanes per (node, head); lane owns 16 channels. Single-pass, DPP reduce,
// exp without max-subtraction. RELU_BIAS=true -> fp16 out (h1), else fp32.
template<int H, bool RELU_BIAS>
__global__ __launch_bounds__(256)
void node_agg_kernel(const __half* __restrict__ xl, const __half* __restrict__ xr,
                     const int* __restrict__ rowptr, const int* __restrict__ srcs,
                     const float* __restrict__ att, const float* __restrict__ bias,
                     __half* __restrict__ outh, float* __restrict__ outf, int n) {
    int g = (blockIdx.x * blockDim.x + threadIdx.x) >> 2;
    int lane = threadIdx.x & 3;
    if (g >= n * H) return;
    int node = g / H, head = g % H;
    const int HC = H * 64;
    int cbase = head * 64 + lane * 16;

    const __half* xrp = xr + (size_t)node * HC + cbase;
    uint4 ur0 = *(const uint4*)(xrp);
    uint4 ur1 = *(const uint4*)(xrp + 8);
    h2 r[8] = {bch2(ur0.x), bch2(ur0.y), bch2(ur0.z), bch2(ur0.w),
               bch2(ur1.x), bch2(ur1.y), bch2(ur1.z), bch2(ur1.w)};
    const float* ap = att + cbase;
    h2 a[8];
    #pragma unroll
    for (int j = 0; j < 8; j++)
        a[j] = h2{(_Float16)ap[2 * j], (_Float16)ap[2 * j + 1]};
    const h2 k02 = {(_Float16)0.2f, (_Float16)0.2f};

    int start = rowptr[node], end = rowptr[node + 1];
    float d = 0.f;
    float acc[16];
    #pragma unroll
    for (int j = 0; j < 16; j++) acc[j] = 0.f;

    #pragma unroll 2
    for (int k = start; k < end; ++k) {
        int src = srcs[k];
        const __half* xlp = xl + (size_t)src * HC + cbase;
        uint4 u0 = *(const uint4*)(xlp);
        uint4 u1 = *(const uint4*)(xlp + 8);
        h2 l[8] = {bch2(u0.x), bch2(u0.y), bch2(u0.z), bch2(u0.w),
                   bch2(u1.x), bch2(u1.y), bch2(u1.z), bch2(u1.w)};
        float pa = 0.f, pb = 0.f;
        #pragma unroll
        for (int j = 0; j < 4; j++) {
            h2 s = l[j] + r[j];
            s = __builtin_elementwise_max(s, s * k02);   // leaky_relu
            pa = __builtin_amdgcn_fdot2(s, a[j], pa, false);
        }
        #pragma unroll
        for (int j = 4; j < 8; j++) {
            h2 s = l[j] + r[j];
            s = __builtin_elementwise_max(s, s * k02);
            pb = __builtin_amdgcn_fdot2(s, a[j], pb, false);
        }
        float p = pa + pb;
        p += dpp_xor1(p);
        p += dpp_xor2(p);          // all 4 lanes hold the full logit
        float w = __expf(p);
        d += w;
        #pragma unroll
        for (int j = 0; j < 8; j++) {
            acc[2 * j]     += w * (float)l[j][0];
            acc[2 * j + 1] += w * (float)l[j][1];
        }
    }

    float inv = 1.f / (d + 1e-16f);
    float o[16];
    #pragma unroll
    for (int j = 0; j < 16; j++) o[j] = acc[j] * inv;
    if (RELU_BIAS) {
        const float* bp = bias + cbase;
        #pragma unroll
        for (int j = 0; j < 16; j++) o[j] = fmaxf(o[j] + bp[j], 0.f);
        __half* op = outh + (size_t)node * HC + cbase;
        uint4 w0, w1;
        __half2 t0 = __floats2half2_rn(o[0], o[1]),  t1 = __floats2half2_rn(o[2], o[3]);
        __half2 t2 = __floats2half2_rn(o[4], o[5]),  t3 = __floats2half2_rn(o[6], o[7]);
        __half2 t4 = __floats2half2_rn(o[8], o[9]),  t5 = __floats2half2_rn(o[10], o[11]);
        __half2 t6 = __floats2half2_rn(o[12], o[13]), t7 = __floats2half2_rn(o[14], o[15]);
        w0.x = *(unsigned int*)&t0; w0.y = *(unsigned int*)&t1;
        w0.z = *(unsigned int*)&t2; w0.w = *(unsigned int*)&t3;
        w1.x = *(unsigned int*)&t4; w1.y = *(unsigned int*)&t5;
        w1.z = *(unsigned int*)&t6; w1.w = *(unsigned int*)&t7;
        *(uint4*)(op) = w0;
        *(uint4*)(op + 8) = w1;
    } else {
        float* op = outf + (size_t)node * HC + cbase;
        #pragma unroll
        for (int q = 0; q < 4; q++)
            *(float4*)(op + q * 4) = make_float4(o[q * 4], o[q * 4 + 1], o[q * 4 + 2], o[q * 4 + 3]);
    }
}

// One wave per node: v2+bias -> log_softmax; write ls fp32 (in place) + fp16.
__global__ __launch_bounds__(256)
void ls_kernel(float* __restrict__ v2, __half* __restrict__ lsh,
               const float* __restrict__ b2, int n) {
    int wave = threadIdx.x >> 6, lane = threadIdx.x & 63;
    int node = blockIdx.x * 4 + wave;
    if (node >= n) return;
    float v = v2[(size_t)node * 64 + lane] + b2[lane];
    float m = v;
    #pragma unroll
    for (int o = 32; o; o >>= 1) m = fmaxf(m, __shfl_xor(m, o));
    float p = expf(v - m);
    float s = p;
    #pragma unroll
    for (int o = 32; o; o >>= 1) s += __shfl_xor(s, o);
    float ls = v - m - logf(s);
    v2[(size_t)node * 64 + lane] = ls;
    lsh[(size_t)node * 64 + lane] = __float2half(ls);
}

// Fused rule-net: per wave (16 rows): T = relu(LS@We1+be1) (MFMA, via LDS
// fp16 transpose), G = T@We2+be2, out = ls + sigmoid(G). K=64, NC=64.
__global__ __launch_bounds__(256)
void gate_kernel(const float* __restrict__ lsf, const __half* __restrict__ lsh,
                 const __half* __restrict__ We1p, const float* __restrict__ be1,
                 const __half* __restrict__ We2p, const float* __restrict__ be2,
                 float* __restrict__ out, int n) {
    __shared__ _Float16 tls[4][16][64];
    int wid = threadIdx.x >> 6, lane = threadIdx.x & 63;
    int row0 = (blockIdx.x * 4 + wid) * 16;
    if (row0 >= n) return;
    int arow = row0 + (lane & 15);
    int koff = (lane >> 4) * 8;
    int colw = lane & 15;
    int rbase = (lane >> 4) * 4;

    half8_t af0 = (arow < n) ? *(const half8_t*)(lsh + (size_t)arow * 64 + koff)
                             : half8_t{0, 0, 0, 0, 0, 0, 0, 0};
    half8_t af1 = (arow < n) ? *(const half8_t*)(lsh + (size_t)arow * 64 + 32 + koff)
                             : half8_t{0, 0, 0, 0, 0, 0, 0, 0};
    #pragma unroll
    for (int t = 0; t < 4; t++) {
        f32x4_t acc = {0.f, 0.f, 0.f, 0.f};
        half8_t b0 = *(const half8_t*)(We1p + (((size_t)t * 2 + 0) * 64 + lane) * 8);
        half8_t b1 = *(const half8_t*)(We1p + (((size_t)t * 2 + 1) * 64 + lane) * 8);
        acc = __builtin_amdgcn_mfma_f32_16x16x32_f16(af0, b0, acc, 0, 0, 0);
        acc = __builtin_amdgcn_mfma_f32_16x16x32_f16(af1, b1, acc, 0, 0, 0);
        float bv = be1[t * 16 + colw];
        #pragma unroll
        for (int r = 0; r < 4; r++)
            tls[wid][rbase + r][t * 16 + colw] = (_Float16)fmaxf(acc[r] + bv, 0.f);
    }
    half8_t tf0 = *(const half8_t*)&tls[wid][lane & 15][koff];
    half8_t tf1 = *(const half8_t*)&tls[wid][lane & 15][32 + koff];
    #pragma unroll
    for (int t = 0; t < 4; t++) {
        f32x4_t acc = {0.f, 0.f, 0.f, 0.f};
        half8_t b0 = *(const half8_t*)(We2p + (((size_t)t * 2 + 0) * 64 + lane) * 8);
        half8_t b1 = *(const half8_t*)(We2p + (((size_t)t * 2 + 1) * 64 + lane) * 8);
        acc = __builtin_amdgcn_mfma_f32_16x16x32_f16(tf0, b0, acc, 0, 0, 0);
        acc = __builtin_amdgcn_mfma_f32_16x16x32_f16(tf1, b1, acc, 0, 0, 0);
        int col = t * 16 + colw;
        float bv = be2[col];
        #pragma unroll
        for (int r = 0; r < 4; r++) {
            int row = row0 + rbase + r;
            if (row < n) {
                float g = 1.f / (1.f + __expf(-(acc[r] + bv)));
                out[(size_t)row * 64 + col] = lsf[(size_t)row * 64 + col] + g;
            }
        }
    }
}

extern "C" void kernel_launch(void* const* d_in, const int* in_sizes, int n_in,
                              void* d_out, int out_size, void* d_ws, size_t ws_size,
                              hipStream_t stream) {
    const float* x    = (const float*)d_in[0];
    const int*   ei   = (const int*)d_in[1];
    const float* Wl1  = (const float*)d_in[2];
    const float* Wr1  = (const float*)d_in[3];
    const float* att1 = (const float*)d_in[4];
    const float* b1   = (const float*)d_in[5];
    const float* Wl2  = (const float*)d_in[6];
    const float* Wr2  = (const float*)d_in[7];
    const float* att2 = (const float*)d_in[8];
    const float* b2   = (const float*)d_in[9];
    const float* We1  = (const float*)d_in[10];
    const float* be1  = (const float*)d_in[11];
    const float* We2  = (const float*)d_in[12];
    const float* be2  = (const float*)d_in[13];
    float* out = (float*)d_out;

    const int n  = in_sizes[0] / 128;
    const int E  = in_sizes[1] / 2;
    const int ET = E + n;
    const int nchunks = (n + 1023) / 1024;

    float* ws = (float*)d_ws;
    size_t o = 0;
    __half* xl1 = (__half*)(ws + o); o += (size_t)n * 64;   // [n,128] fp16
    __half* xr1 = (__half*)(ws + o); o += (size_t)n * 64;   // [n,128] fp16
    __half* xh  = (__half*)(ws + o); o += (size_t)n * 64;   // x as fp16 [n,128]
    __half* h1h = (__half*)(ws + o); o += (size_t)n * 64;   // h1 fp16 [n,128]
    float*  v2  = ws + o;            o += (size_t)n * 64;   // fp32 [n,64] -> ls in place
    __half* lsh = (__half*)(ws + o); o += (size_t)n * 32;   // ls fp16 [n,64]
    __half* Wp1 = (__half*)(ws + o); o += 16384;            // 32768 halves
    __half* Wp2 = (__half*)(ws + o); o += 8192;             // 16384 halves
    __half* We1p = (__half*)(ws + o); o += 2048;            // 4096 halves
    __half* We2p = (__half*)(ws + o); o += 2048;            // 4096 halves
    int* rowptr   = (int*)(ws + o); o += (size_t)(n + 1);
    int* cursorP  = (int*)(ws + o); o += (size_t)n * CSTR;  // padded counters
    int* srcs     = (int*)(ws + o); o += (size_t)ET;
    int* partials = (int*)(ws + o); o += 1024;
    __half* xl2 = xl1;                     // [n,64] fp16 (reuses dead xl1 region)
    __half* xr2 = xl1 + (size_t)n * 64;
    int* degP = cursorP;                   // deg aliases cursor (rebuilt by scan_apply)
    float* lsf = v2;

    const int BS = 256;
    auto blocks = [](long long t, int bs) { return (int)((t + bs - 1) / bs); };

    // ---- CSR build (by dst), self-loops via deg init = 1; 128B-padded counters ----
    fill_strided_kernel<<<blocks(n, BS), BS, 0, stream>>>(degP, 1, n);
    hist_kernel<<<blocks(E, BS), BS, 0, stream>>>(ei, degP, E);
    scan_block_kernel<<<nchunks, 1024, 0, stream>>>(degP, rowptr, partials, n);
    scan_partials_kernel<<<1, 1024, 0, stream>>>(partials, nchunks);
    scan_apply_kernel<<<nchunks, 1024, 0, stream>>>(rowptr, partials, cursorP, n);
    scatter_kernel<<<blocks(ET, BS), BS, 0, stream>>>(ei, cursorP, srcs, E, ET);

    // ---- one-time conversions / packs ----
    f2h_kernel<<<blocks((long long)n * 32, BS), BS, 0, stream>>>(x, xh, (long long)n * 32);
    pack_w_kernel<256, 128, true><<<16, 256, 0, stream>>>(Wl1, Wr1, Wp1);
    pack_w_kernel<128, 128, true><<<8, 256, 0, stream>>>(Wl2, Wr2, Wp2);
    pack_w_kernel<64, 64, false><<<2, 256, 0, stream>>>(We1, nullptr, We1p);
    pack_w_kernel<64, 64, false><<<2, 256, 0, stream>>>(We2, nullptr, We2p);

    // ---- layer 1 ----
    const int rt = (n + 15) / 16;          // row tiles
    gemm_mfma_kernel<256, 128><<<rt, 256, 0, stream>>>(xh, Wp1, xl1, xr1, n);
    node_agg_kernel<2, true><<<blocks((long long)n * 2 * 4, BS), BS, 0, stream>>>(
        xl1, xr1, rowptr, srcs, att1, b1, h1h, nullptr, n);

    // ---- layer 2 ----
    gemm_mfma_kernel<128, 128><<<rt, 256, 0, stream>>>(h1h, Wp2, xl2, xr2, n);
    node_agg_kernel<1, false><<<blocks((long long)n * 4, BS), BS, 0, stream>>>(
        xl2, xr2, rowptr, srcs, att2, nullptr, nullptr, v2, n);

    // ---- finalize: log_softmax, then fused MFMA rule-net ----
    ls_kernel<<<(n + 3) / 4, BS, 0, stream>>>(v2, lsh, b2, n);
    gate_kernel<<<(n + 63) / 64, BS, 0, stream>>>(lsf, lsh, We1p, be1, We2p, be2, out, n);
}

// Round 10
// 215.000 us; speedup vs baseline: 2.0021x; 1.1581x over previous
//
#include <hip/hip_runtime.h>
#include <hip/hip_bf16.h>
#include <hip/hip_fp16.h>
#include <math.h>

// ---------------------------------------------------------------------------
// GATv2 x2 + log_softmax + gated rule-net.
// R9: atomic scatter (59us, bound by cross-XCD partial-line HBM writebacks:
// 57MB @ ~1TB/s) replaced by 2-pass bucket scatter: pass A buckets edges by
// dst>>9 with LDS ranks (coalesced pair writes), pass B gives each bucket's
// contiguous srcs region to ONE block (LDS cursors, full-line single-XCD
// writes). Bucket bases derived from rowptr -- no extra scan.
// ---------------------------------------------------------------------------

typedef _Float16 h2 __attribute__((ext_vector_type(2)));
typedef _Float16 half8_t __attribute__((ext_vector_type(8)));
typedef float f32x4_t __attribute__((ext_vector_type(4)));
union H2U { unsigned int u; h2 h; };
__device__ inline h2 bch2(unsigned int x) { H2U t; t.u = x; return t.h; }

constexpr int CSTR = 32;     // padded counter stride (ints)
constexpr int BKT_W = 512;   // dsts per bucket
constexpr int PA_EPT = 8;    // edges per thread, pass A

__device__ inline float dpp_xor1(float x) {
    int v = __builtin_amdgcn_mov_dpp(__builtin_bit_cast(int, x), 0xB1, 0xF, 0xF, true);
    return __builtin_bit_cast(float, v);
}
__device__ inline float dpp_xor2(float x) {
    int v = __builtin_amdgcn_mov_dpp(__builtin_bit_cast(int, x), 0x4E, 0xF, 0xF, true);
    return __builtin_bit_cast(float, v);
}

__global__ void fill_strided_kernel(int* __restrict__ p, int v, int count) {
    int i = blockIdx.x * blockDim.x + threadIdx.x;
    if (i < count) p[(size_t)i * CSTR] = v;
}

__global__ void hist_kernel(const int* __restrict__ ei, int* __restrict__ deg, int E) {
    int e = blockIdx.x * blockDim.x + threadIdx.x;
    if (e < E) atomicAdd(&deg[(size_t)ei[E + e] * CSTR], 1);
}

__global__ __launch_bounds__(1024)
void scan_block_kernel(const int* __restrict__ deg, int* __restrict__ rowptr,
                       int* __restrict__ partials, int n) {
    __shared__ int s[1024];
    int i = blockIdx.x * 1024 + threadIdx.x;
    int v = (i < n) ? deg[(size_t)i * CSTR] : 0;
    s[threadIdx.x] = v;
    __syncthreads();
    #pragma unroll
    for (int off = 1; off < 1024; off <<= 1) {
        int t = (threadIdx.x >= off) ? s[threadIdx.x - off] : 0;
        __syncthreads();
        s[threadIdx.x] += t;
        __syncthreads();
    }
    if (i < n) rowptr[i + 1] = s[threadIdx.x];
    if (threadIdx.x == 1023) partials[blockIdx.x] = s[1023];
}

__global__ __launch_bounds__(1024)
void scan_partials_kernel(int* __restrict__ partials, int nparts) {
    __shared__ int s[1024];
    int v = (threadIdx.x < nparts) ? partials[threadIdx.x] : 0;
    s[threadIdx.x] = v;
    __syncthreads();
    #pragma unroll
    for (int off = 1; off < 1024; off <<= 1) {
        int t = (threadIdx.x >= off) ? s[threadIdx.x - off] : 0;
        __syncthreads();
        s[threadIdx.x] += t;
        __syncthreads();
    }
    if (threadIdx.x < nparts) partials[threadIdx.x] = s[threadIdx.x] - v;  // exclusive
}

__global__ __launch_bounds__(1024)
void scan_apply_kernel(int* __restrict__ rowptr, const int* __restrict__ partials, int n) {
    int i = blockIdx.x * 1024 + threadIdx.x;
    if (i == 0) rowptr[0] = 0;
    if (i < n) rowptr[i + 1] += partials[blockIdx.x];
}

// seed bucket cursors: bcur[b] = rowptr[b*BKT_W] - b*BKT_W (pairs exclude self-loops)
__global__ void bucket_seed_kernel(const int* __restrict__ rowptr, int* __restrict__ bcur,
                                   int nb) {
    int b = blockIdx.x * blockDim.x + threadIdx.x;
    if (b < nb) bcur[(size_t)b * CSTR] = rowptr[b * BKT_W] - b * BKT_W;
}

// Pass A: partition edges into buckets of BKT_W dsts. LDS hist + ranks; one
// global atomic per (block,bucket); coalesced-chunk pair writes.
__global__ __launch_bounds__(1024)
void bucket_pass_kernel(const int* __restrict__ ei, int E,
                        int* __restrict__ bcur, uint2* __restrict__ pairs, int nb) {
    __shared__ int lhist[128];
    __shared__ int lbase[128];
    int e0 = blockIdx.x * (1024 * PA_EPT);
    if (threadIdx.x < 128) lhist[threadIdx.x] = 0;
    __syncthreads();
    int mysrc[PA_EPT], mydst[PA_EPT], myrank[PA_EPT];
    #pragma unroll
    for (int j = 0; j < PA_EPT; j++) {
        int e = e0 + j * 1024 + threadIdx.x;
        if (e < E) {
            mysrc[j] = ei[e];
            mydst[j] = ei[E + e];
            myrank[j] = atomicAdd(&lhist[mydst[j] >> 9], 1);
        } else mydst[j] = -1;
    }
    __syncthreads();
    if (threadIdx.x < nb && lhist[threadIdx.x] > 0)
        lbase[threadIdx.x] = atomicAdd(&bcur[(size_t)threadIdx.x * CSTR], lhist[threadIdx.x]);
    __syncthreads();
    #pragma unroll
    for (int j = 0; j < PA_EPT; j++) {
        if (mydst[j] >= 0) {
            int b = mydst[j] >> 9;
            pairs[(size_t)lbase[b] + myrank[j]] = make_uint2((unsigned)mysrc[j], (unsigned)mydst[j]);
        }
    }
}

// Pass B: one block per bucket owns srcs[rowptr[lo] .. rowptr[hi]) -- single
// XCD writes the whole region (L2-merged full lines). Self-loop slot first.
__global__ __launch_bounds__(1024)
void bucket_scatter_kernel(const uint2* __restrict__ pairs, const int* __restrict__ rowptr,
                           int* __restrict__ srcs, int n) {
    __shared__ int cur[BKT_W];
    int b = blockIdx.x;
    int lo = b * BKT_W;
    int hi = min(lo + BKT_W, n);
    for (int d = lo + (int)threadIdx.x; d < hi; d += 1024) {
        int c = rowptr[d];
        srcs[c] = d;           // self-loop
        cur[d - lo] = c + 1;
    }
    __syncthreads();
    int base = rowptr[lo] - lo;
    int endd = rowptr[hi] - hi;
    for (int k = base + (int)threadIdx.x; k < endd; k += 1024) {
        uint2 pr = pairs[k];
        int pos = atomicAdd(&cur[(int)pr.y - lo], 1);
        srcs[pos] = (int)pr.x;
    }
}

// fp32 -> fp16 convert (4 floats / thread)
__global__ void f2h_kernel(const float* __restrict__ in, __half* __restrict__ out,
                           long long count4) {
    long long i = (long long)blockIdx.x * blockDim.x + threadIdx.x;
    if (i >= count4) return;
    float4 v = *(const float4*)(in + i * 4);
    __half2 h01 = __floats2half2_rn(v.x, v.y);
    __half2 h23 = __floats2half2_rn(v.z, v.w);
    uint2 u;
    u.x = *(unsigned int*)&h01;
    u.y = *(unsigned int*)&h23;
    *(uint2*)(out + i * 4) = u;
}

// Pack weights into MFMA B-frag layout (16x16x32 f16)
template<int NC, int K, bool DUAL>
__global__ void pack_w_kernel(const float* __restrict__ W0, const float* __restrict__ W1,
                              __half* __restrict__ Wp) {
    constexpr int KC = K / 32;
    constexpr int M = DUAL ? NC / 2 : NC;
    int idx = blockIdx.x * 256 + threadIdx.x;
    if (idx >= (NC / 16) * KC * 64) return;
    int lane = idx & 63;
    int c = (idx >> 6) % KC;
    int t = idx / (64 * KC);
    int col = t * 16 + (lane & 15);
    int k0 = c * 32 + (lane >> 4) * 8;
    __half tmp[8];
    #pragma unroll
    for (int e = 0; e < 8; e++) {
        int k = k0 + e;
        float v;
        if (DUAL) v = (col < M) ? W0[(size_t)k * M + col] : W1[(size_t)k * M + (col - M)];
        else      v = W0[(size_t)k * M + col];
        tmp[e] = __float2half(v);
    }
    *(uint4*)(Wp + (size_t)idx * 8) = *(uint4*)tmp;
}

// MFMA dual GEMM: one wave per (16-row tile, col quarter); no LDS.
template<int NC, int K>
__global__ __launch_bounds__(256)
void gemm_mfma_kernel(const __half* __restrict__ A, const __half* __restrict__ Wp,
                      __half* __restrict__ Y0, __half* __restrict__ Y1, int n) {
    constexpr int KC = K / 32;
    constexpr int NT = NC / 16;
    constexpr int NTW = NT / 4;
    constexpr int M = NC / 2;
    int gw = (int)((blockIdx.x * 256 + threadIdx.x) >> 6);
    int lane = threadIdx.x & 63;
    int rt = gw >> 2;
    int wq = gw & 3;
    int row0 = rt * 16;
    if (row0 >= n) return;
    int arow = row0 + (lane & 15);
    int koff = (lane >> 4) * 8;
    half8_t af[KC];
    #pragma unroll
    for (int c = 0; c < KC; c++) {
        af[c] = (arow < n) ? *(const half8_t*)(A + (size_t)arow * K + c * 32 + koff)
                           : half8_t{0, 0, 0, 0, 0, 0, 0, 0};
    }
    #pragma unroll
    for (int t4 = 0; t4 < NTW; t4++) {
        int t = wq * NTW + t4;
        f32x4_t acc = {0.f, 0.f, 0.f, 0.f};
        #pragma unroll
        for (int c = 0; c < KC; c++) {
            half8_t bf = *(const half8_t*)(Wp + (((size_t)t * KC + c) * 64 + lane) * 8);
            acc = __builtin_amdgcn_mfma_f32_16x16x32_f16(af[c], bf, acc, 0, 0, 0);
        }
        int col = t * 16 + (lane & 15);
        #pragma unroll
        for (int r = 0; r < 4; r++) {
            int row = row0 + (lane >> 4) * 4 + r;
            if (row < n) {
                __half v = __float2half(acc[r]);
                if (col < M) Y0[(size_t)row * M + col] = v;
                else         Y1[(size_t)row * M + (col - M)] = v;
            }
        }
    }
}

// 4 lanes per (node, head); lane owns 16 channels. Single-pass, DPP reduce,
// exp without max-subtraction. RELU_BIAS=true -> fp16 out (h1), else fp32.
template<int H, bool RELU_BIAS>
__global__ __launch_bounds__(256)
void node_agg_kernel(const __half* __restrict__ xl, const __half* __restrict__ xr,
                     const int* __restrict__ rowptr, const int* __restrict__ srcs,
                     const float* __restrict__ att, const float* __restrict__ bias,
                     __half* __restrict__ outh, float* __restrict__ outf, int n) {
    int g = (blockIdx.x * blockDim.x + threadIdx.x) >> 2;
    int lane = threadIdx.x & 3;
    if (g >= n * H) return;
    int node = g / H, head = g % H;
    const int HC = H * 64;
    int cbase = head * 64 + lane * 16;

    const __half* xrp = xr + (size_t)node * HC + cbase;
    uint4 ur0 = *(const uint4*)(xrp);
    uint4 ur1 = *(const uint4*)(xrp + 8);
    h2 r[8] = {bch2(ur0.x), bch2(ur0.y), bch2(ur0.z), bch2(ur0.w),
               bch2(ur1.x), bch2(ur1.y), bch2(ur1.z), bch2(ur1.w)};
    const float* ap = att + cbase;
    h2 a[8];
    #pragma unroll
    for (int j = 0; j < 8; j++)
        a[j] = h2{(_Float16)ap[2 * j], (_Float16)ap[2 * j + 1]};
    const h2 k02 = {(_Float16)0.2f, (_Float16)0.2f};

    int start = rowptr[node], end = rowptr[node + 1];
    float d = 0.f;
    float acc[16];
    #pragma unroll
    for (int j = 0; j < 16; j++) acc[j] = 0.f;

    #pragma unroll 2
    for (int k = start; k < end; ++k) {
        int src = srcs[k];
        const __half* xlp = xl + (size_t)src * HC + cbase;
        uint4 u0 = *(const uint4*)(xlp);
        uint4 u1 = *(const uint4*)(xlp + 8);
        h2 l[8] = {bch2(u0.x), bch2(u0.y), bch2(u0.z), bch2(u0.w),
                   bch2(u1.x), bch2(u1.y), bch2(u1.z), bch2(u1.w)};
        float pa = 0.f, pb = 0.f;
        #pragma unroll
        for (int j = 0; j < 4; j++) {
            h2 s = l[j] + r[j];
            s = __builtin_elementwise_max(s, s * k02);   // leaky_relu
            pa = __builtin_amdgcn_fdot2(s, a[j], pa, false);
        }
        #pragma unroll
        for (int j = 4; j < 8; j++) {
            h2 s = l[j] + r[j];
            s = __builtin_elementwise_max(s, s * k02);
            pb = __builtin_amdgcn_fdot2(s, a[j], pb, false);
        }
        float p = pa + pb;
        p += dpp_xor1(p);
        p += dpp_xor2(p);          // all 4 lanes hold the full logit
        float w = __expf(p);
        d += w;
        #pragma unroll
        for (int j = 0; j < 8; j++) {
            acc[2 * j]     += w * (float)l[j][0];
            acc[2 * j + 1] += w * (float)l[j][1];
        }
    }

    float inv = 1.f / (d + 1e-16f);
    float o[16];
    #pragma unroll
    for (int j = 0; j < 16; j++) o[j] = acc[j] * inv;
    if (RELU_BIAS) {
        const float* bp = bias + cbase;
        #pragma unroll
        for (int j = 0; j < 16; j++) o[j] = fmaxf(o[j] + bp[j], 0.f);
        __half* op = outh + (size_t)node * HC + cbase;
        uint4 w0, w1;
        __half2 t0 = __floats2half2_rn(o[0], o[1]),  t1 = __floats2half2_rn(o[2], o[3]);
        __half2 t2 = __floats2half2_rn(o[4], o[5]),  t3 = __floats2half2_rn(o[6], o[7]);
        __half2 t4 = __floats2half2_rn(o[8], o[9]),  t5 = __floats2half2_rn(o[10], o[11]);
        __half2 t6 = __floats2half2_rn(o[12], o[13]), t7 = __floats2half2_rn(o[14], o[15]);
        w0.x = *(unsigned int*)&t0; w0.y = *(unsigned int*)&t1;
        w0.z = *(unsigned int*)&t2; w0.w = *(unsigned int*)&t3;
        w1.x = *(unsigned int*)&t4; w1.y = *(unsigned int*)&t5;
        w1.z = *(unsigned int*)&t6; w1.w = *(unsigned int*)&t7;
        *(uint4*)(op) = w0;
        *(uint4*)(op + 8) = w1;
    } else {
        float* op = outf + (size_t)node * HC + cbase;
        #pragma unroll
        for (int q = 0; q < 4; q++)
            *(float4*)(op + q * 4) = make_float4(o[q * 4], o[q * 4 + 1], o[q * 4 + 2], o[q * 4 + 3]);
    }
}

// One wave per node: v2+bias -> log_softmax; write ls fp32 (in place) + fp16.
__global__ __launch_bounds__(256)
void ls_kernel(float* __restrict__ v2, __half* __restrict__ lsh,
               const float* __restrict__ b2, int n) {
    int wave = threadIdx.x >> 6, lane = threadIdx.x & 63;
    int node = blockIdx.x * 4 + wave;
    if (node >= n) return;
    float v = v2[(size_t)node * 64 + lane] + b2[lane];
    float m = v;
    #pragma unroll
    for (int o = 32; o; o >>= 1) m = fmaxf(m, __shfl_xor(m, o));
    float p = expf(v - m);
    float s = p;
    #pragma unroll
    for (int o = 32; o; o >>= 1) s += __shfl_xor(s, o);
    float ls = v - m - logf(s);
    v2[(size_t)node * 64 + lane] = ls;
    lsh[(size_t)node * 64 + lane] = __float2half(ls);
}

// Fused rule-net: T = relu(LS@We1+be1) (MFMA via LDS fp16 transpose),
// G = T@We2+be2, out = ls + sigmoid(G).
__global__ __launch_bounds__(256)
void gate_kernel(const float* __restrict__ lsf, const __half* __restrict__ lsh,
                 const __half* __restrict__ We1p, const float* __restrict__ be1,
                 const __half* __restrict__ We2p, const float* __restrict__ be2,
                 float* __restrict__ out, int n) {
    __shared__ _Float16 tls[4][16][64];
    int wid = threadIdx.x >> 6, lane = threadIdx.x & 63;
    int row0 = (blockIdx.x * 4 + wid) * 16;
    if (row0 >= n) return;
    int arow = row0 + (lane & 15);
    int koff = (lane >> 4) * 8;
    int colw = lane & 15;
    int rbase = (lane >> 4) * 4;

    half8_t af0 = (arow < n) ? *(const half8_t*)(lsh + (size_t)arow * 64 + koff)
                             : half8_t{0, 0, 0, 0, 0, 0, 0, 0};
    half8_t af1 = (arow < n) ? *(const half8_t*)(lsh + (size_t)arow * 64 + 32 + koff)
                             : half8_t{0, 0, 0, 0, 0, 0, 0, 0};
    #pragma unroll
    for (int t = 0; t < 4; t++) {
        f32x4_t acc = {0.f, 0.f, 0.f, 0.f};
        half8_t b0 = *(const half8_t*)(We1p + (((size_t)t * 2 + 0) * 64 + lane) * 8);
        half8_t b1 = *(const half8_t*)(We1p + (((size_t)t * 2 + 1) * 64 + lane) * 8);
        acc = __builtin_amdgcn_mfma_f32_16x16x32_f16(af0, b0, acc, 0, 0, 0);
        acc = __builtin_amdgcn_mfma_f32_16x16x32_f16(af1, b1, acc, 0, 0, 0);
        float bv = be1[t * 16 + colw];
        #pragma unroll
        for (int r = 0; r < 4; r++)
            tls[wid][rbase + r][t * 16 + colw] = (_Float16)fmaxf(acc[r] + bv, 0.f);
    }
    half8_t tf0 = *(const half8_t*)&tls[wid][lane & 15][koff];
    half8_t tf1 = *(const half8_t*)&tls[wid][lane & 15][32 + koff];
    #pragma unroll
    for (int t = 0; t < 4; t++) {
        f32x4_t acc = {0.f, 0.f, 0.f, 0.f};
        half8_t b0 = *(const half8_t*)(We2p + (((size_t)t * 2 + 0) * 64 + lane) * 8);
        half8_t b1 = *(const half8_t*)(We2p + (((size_t)t * 2 + 1) * 64 + lane) * 8);
        acc = __builtin_amdgcn_mfma_f32_16x16x32_f16(tf0, b0, acc, 0, 0, 0);
        acc = __builtin_amdgcn_mfma_f32_16x16x32_f16(tf1, b1, acc, 0, 0, 0);
        int col = t * 16 + colw;
        float bv = be2[col];
        #pragma unroll
        for (int r = 0; r < 4; r++) {
            int row = row0 + rbase + r;
            if (row < n) {
                float g = 1.f / (1.f + __expf(-(acc[r] + bv)));
                out[(size_t)row * 64 + col] = lsf[(size_t)row * 64 + col] + g;
            }
        }
    }
}

extern "C" void kernel_launch(void* const* d_in, const int* in_sizes, int n_in,
                              void* d_out, int out_size, void* d_ws, size_t ws_size,
                              hipStream_t stream) {
    const float* x    = (const float*)d_in[0];
    const int*   ei   = (const int*)d_in[1];
    const float* Wl1  = (const float*)d_in[2];
    const float* Wr1  = (const float*)d_in[3];
    const float* att1 = (const float*)d_in[4];
    const float* b1   = (const float*)d_in[5];
    const float* Wl2  = (const float*)d_in[6];
    const float* Wr2  = (const float*)d_in[7];
    const float* att2 = (const float*)d_in[8];
    const float* b2   = (const float*)d_in[9];
    const float* We1  = (const float*)d_in[10];
    const float* be1  = (const float*)d_in[11];
    const float* We2  = (const float*)d_in[12];
    const float* be2  = (const float*)d_in[13];
    float* out = (float*)d_out;

    const int n  = in_sizes[0] / 128;
    const int E  = in_sizes[1] / 2;
    const int ET = E + n;
    const int nchunks = (n + 1023) / 1024;
    const int nb = (n + BKT_W - 1) / BKT_W;

    float* ws = (float*)d_ws;
    size_t o = 0;
    __half* xl1 = (__half*)(ws + o); o += (size_t)n * 64;   // [n,128] fp16
    __half* xr1 = (__half*)(ws + o); o += (size_t)n * 64;   // [n,128] fp16
    __half* xh  = (__half*)(ws + o); o += (size_t)n * 64;   // x as fp16 [n,128]
    __half* h1h = (__half*)(ws + o); o += (size_t)n * 64;   // h1 fp16 [n,128]
    float*  v2  = ws + o;            o += (size_t)n * 64;   // fp32 [n,64] -> ls in place
    __half* lsh = (__half*)(ws + o); o += (size_t)n * 32;   // ls fp16 [n,64]
    __half* Wp1 = (__half*)(ws + o); o += 16384;
    __half* Wp2 = (__half*)(ws + o); o += 8192;
    __half* We1p = (__half*)(ws + o); o += 2048;
    __half* We2p = (__half*)(ws + o); o += 2048;
    int* rowptr   = (int*)(ws + o); o += (size_t)(n + 1);
    int* degP     = (int*)(ws + o); o += (size_t)n * CSTR;  // padded deg counters
    int* srcs     = (int*)(ws + o); o += (size_t)ET;
    int* partials = (int*)(ws + o); o += 1024;
    uint2* pairs  = (uint2*)(ws + o); o += (size_t)E * 2;   // bucketed (src,dst)
    int* bcur     = (int*)(ws + o); o += 128 * CSTR;        // bucket cursors
    __half* xl2 = xl1;                     // [n,64] fp16 (reuses dead xl1 region)
    __half* xr2 = xl1 + (size_t)n * 64;
    float* lsf = v2;

    const int BS = 256;
    auto blocks = [](long long t, int bs) { return (int)((t + bs - 1) / bs); };

    // ---- CSR build (by dst), self-loops via deg init = 1 ----
    fill_strided_kernel<<<blocks(n, BS), BS, 0, stream>>>(degP, 1, n);
    hist_kernel<<<blocks(E, BS), BS, 0, stream>>>(ei, degP, E);
    scan_block_kernel<<<nchunks, 1024, 0, stream>>>(degP, rowptr, partials, n);
    scan_partials_kernel<<<1, 1024, 0, stream>>>(partials, nchunks);
    scan_apply_kernel<<<nchunks, 1024, 0, stream>>>(rowptr, partials, n);
    // 2-pass bucket scatter
    bucket_seed_kernel<<<1, 128, 0, stream>>>(rowptr, bcur, nb);
    bucket_pass_kernel<<<blocks(E, 1024 * PA_EPT), 1024, 0, stream>>>(ei, E, bcur, pairs, nb);
    bucket_scatter_kernel<<<nb, 1024, 0, stream>>>(pairs, rowptr, srcs, n);

    // ---- one-time conversions / packs ----
    f2h_kernel<<<blocks((long long)n * 32, BS), BS, 0, stream>>>(x, xh, (long long)n * 32);
    pack_w_kernel<256, 128, true><<<16, 256, 0, stream>>>(Wl1, Wr1, Wp1);
    pack_w_kernel<128, 128, true><<<8, 256, 0, stream>>>(Wl2, Wr2, Wp2);
    pack_w_kernel<64, 64, false><<<2, 256, 0, stream>>>(We1, nullptr, We1p);
    pack_w_kernel<64, 64, false><<<2, 256, 0, stream>>>(We2, nullptr, We2p);

    // ---- layer 1 ----
    const int rt = (n + 15) / 16;          // row tiles
    gemm_mfma_kernel<256, 128><<<rt, 256, 0, stream>>>(xh, Wp1, xl1, xr1, n);
    node_agg_kernel<2, true><<<blocks((long long)n * 2 * 4, BS), BS, 0, stream>>>(
        xl1, xr1, rowptr, srcs, att1, b1, h1h, nullptr, n);

    // ---- layer 2 ----
    gemm_mfma_kernel<128, 128><<<rt, 256, 0, stream>>>(h1h, Wp2, xl2, xr2, n);
    node_agg_kernel<1, false><<<blocks((long long)n * 4, BS), BS, 0, stream>>>(
        xl2, xr2, rowptr, srcs, att2, nullptr, nullptr, v2, n);

    // ---- finalize: log_softmax, then fused MFMA rule-net ----
    ls_kernel<<<(n + 3) / 4, BS, 0, stream>>>(v2, lsh, b2, n);
    gate_kernel<<<(n + 63) / 64, BS, 0, stream>>>(lsf, lsh, We1p, be1, We2p, be2, out, n);
}

// Round 11
// 206.366 us; speedup vs baseline: 2.0859x; 1.0418x over previous
//
#include <hip/hip_runtime.h>
#include <hip/hip_bf16.h>
#include <hip/hip_fp16.h>
#include <math.h>

// ---------------------------------------------------------------------------
// GATv2 x2 + log_softmax + gated rule-net.
// R10: node_agg made request/latency-optimal: (a) layer-1 uses 8-lane groups
// (one group per node, both heads; 256B row fetched as one wave segment,
// srcs read once); (b) depth-2 register software pipeline (named A/B bufs);
// (c) log_softmax fused into layer-2 agg (group holds full row; quad-DPP
// max/sum) -- ls_kernel eliminated.
// ---------------------------------------------------------------------------

typedef _Float16 h2 __attribute__((ext_vector_type(2)));
typedef _Float16 half8_t __attribute__((ext_vector_type(8)));
typedef float f32x4_t __attribute__((ext_vector_type(4)));
union H2U { unsigned int u; h2 h; };
__device__ inline h2 bch2(unsigned int x) { H2U t; t.u = x; return t.h; }

constexpr int CSTR = 32;     // padded counter stride (ints)
constexpr int BKT_W = 512;   // dsts per bucket
constexpr int PA_EPT = 8;    // edges per thread, pass A

__device__ inline float dpp_xor1(float x) {
    int v = __builtin_amdgcn_mov_dpp(__builtin_bit_cast(int, x), 0xB1, 0xF, 0xF, true);
    return __builtin_bit_cast(float, v);
}
__device__ inline float dpp_xor2(float x) {
    int v = __builtin_amdgcn_mov_dpp(__builtin_bit_cast(int, x), 0x4E, 0xF, 0xF, true);
    return __builtin_bit_cast(float, v);
}

__global__ void fill_strided_kernel(int* __restrict__ p, int v, int count) {
    int i = blockIdx.x * blockDim.x + threadIdx.x;
    if (i < count) p[(size_t)i * CSTR] = v;
}

__global__ void hist_kernel(const int* __restrict__ ei, int* __restrict__ deg, int E) {
    int e = blockIdx.x * blockDim.x + threadIdx.x;
    if (e < E) atomicAdd(&deg[(size_t)ei[E + e] * CSTR], 1);
}

__global__ __launch_bounds__(1024)
void scan_block_kernel(const int* __restrict__ deg, int* __restrict__ rowptr,
                       int* __restrict__ partials, int n) {
    __shared__ int s[1024];
    int i = blockIdx.x * 1024 + threadIdx.x;
    int v = (i < n) ? deg[(size_t)i * CSTR] : 0;
    s[threadIdx.x] = v;
    __syncthreads();
    #pragma unroll
    for (int off = 1; off < 1024; off <<= 1) {
        int t = (threadIdx.x >= off) ? s[threadIdx.x - off] : 0;
        __syncthreads();
        s[threadIdx.x] += t;
        __syncthreads();
    }
    if (i < n) rowptr[i + 1] = s[threadIdx.x];
    if (threadIdx.x == 1023) partials[blockIdx.x] = s[1023];
}

__global__ __launch_bounds__(1024)
void scan_partials_kernel(int* __restrict__ partials, int nparts) {
    __shared__ int s[1024];
    int v = (threadIdx.x < nparts) ? partials[threadIdx.x] : 0;
    s[threadIdx.x] = v;
    __syncthreads();
    #pragma unroll
    for (int off = 1; off < 1024; off <<= 1) {
        int t = (threadIdx.x >= off) ? s[threadIdx.x - off] : 0;
        __syncthreads();
        s[threadIdx.x] += t;
        __syncthreads();
    }
    if (threadIdx.x < nparts) partials[threadIdx.x] = s[threadIdx.x] - v;  // exclusive
}

__global__ __launch_bounds__(1024)
void scan_apply_kernel(int* __restrict__ rowptr, const int* __restrict__ partials, int n) {
    int i = blockIdx.x * 1024 + threadIdx.x;
    if (i == 0) rowptr[0] = 0;
    if (i < n) rowptr[i + 1] += partials[blockIdx.x];
}

__global__ void bucket_seed_kernel(const int* __restrict__ rowptr, int* __restrict__ bcur,
                                   int nb) {
    int b = blockIdx.x * blockDim.x + threadIdx.x;
    if (b < nb) bcur[(size_t)b * CSTR] = rowptr[b * BKT_W] - b * BKT_W;
}

// Pass A: partition edges into buckets of BKT_W dsts.
__global__ __launch_bounds__(1024)
void bucket_pass_kernel(const int* __restrict__ ei, int E,
                        int* __restrict__ bcur, uint2* __restrict__ pairs, int nb) {
    __shared__ int lhist[128];
    __shared__ int lbase[128];
    int e0 = blockIdx.x * (1024 * PA_EPT);
    if (threadIdx.x < 128) lhist[threadIdx.x] = 0;
    __syncthreads();
    int mysrc[PA_EPT], mydst[PA_EPT], myrank[PA_EPT];
    #pragma unroll
    for (int j = 0; j < PA_EPT; j++) {
        int e = e0 + j * 1024 + threadIdx.x;
        if (e < E) {
            mysrc[j] = ei[e];
            mydst[j] = ei[E + e];
            myrank[j] = atomicAdd(&lhist[mydst[j] >> 9], 1);
        } else mydst[j] = -1;
    }
    __syncthreads();
    if (threadIdx.x < nb && lhist[threadIdx.x] > 0)
        lbase[threadIdx.x] = atomicAdd(&bcur[(size_t)threadIdx.x * CSTR], lhist[threadIdx.x]);
    __syncthreads();
    #pragma unroll
    for (int j = 0; j < PA_EPT; j++) {
        if (mydst[j] >= 0) {
            int b = mydst[j] >> 9;
            pairs[(size_t)lbase[b] + myrank[j]] = make_uint2((unsigned)mysrc[j], (unsigned)mydst[j]);
        }
    }
}

// Pass B: one block per bucket owns its contiguous srcs region.
__global__ __launch_bounds__(1024)
void bucket_scatter_kernel(const uint2* __restrict__ pairs, const int* __restrict__ rowptr,
                           int* __restrict__ srcs, int n) {
    __shared__ int cur[BKT_W];
    int b = blockIdx.x;
    int lo = b * BKT_W;
    int hi = min(lo + BKT_W, n);
    for (int d = lo + (int)threadIdx.x; d < hi; d += 1024) {
        int c = rowptr[d];
        srcs[c] = d;           // self-loop
        cur[d - lo] = c + 1;
    }
    __syncthreads();
    int base = rowptr[lo] - lo;
    int endd = rowptr[hi] - hi;
    for (int k = base + (int)threadIdx.x; k < endd; k += 1024) {
        uint2 pr = pairs[k];
        int pos = atomicAdd(&cur[(int)pr.y - lo], 1);
        srcs[pos] = (int)pr.x;
    }
}

// fp32 -> fp16 convert (4 floats / thread)
__global__ void f2h_kernel(const float* __restrict__ in, __half* __restrict__ out,
                           long long count4) {
    long long i = (long long)blockIdx.x * blockDim.x + threadIdx.x;
    if (i >= count4) return;
    float4 v = *(const float4*)(in + i * 4);
    __half2 h01 = __floats2half2_rn(v.x, v.y);
    __half2 h23 = __floats2half2_rn(v.z, v.w);
    uint2 u;
    u.x = *(unsigned int*)&h01;
    u.y = *(unsigned int*)&h23;
    *(uint2*)(out + i * 4) = u;
}

// Pack weights into MFMA B-frag layout (16x16x32 f16)
template<int NC, int K, bool DUAL>
__global__ void pack_w_kernel(const float* __restrict__ W0, const float* __restrict__ W1,
                              __half* __restrict__ Wp) {
    constexpr int KC = K / 32;
    constexpr int M = DUAL ? NC / 2 : NC;
    int idx = blockIdx.x * 256 + threadIdx.x;
    if (idx >= (NC / 16) * KC * 64) return;
    int lane = idx & 63;
    int c = (idx >> 6) % KC;
    int t = idx / (64 * KC);
    int col = t * 16 + (lane & 15);
    int k0 = c * 32 + (lane >> 4) * 8;
    __half tmp[8];
    #pragma unroll
    for (int e = 0; e < 8; e++) {
        int k = k0 + e;
        float v;
        if (DUAL) v = (col < M) ? W0[(size_t)k * M + col] : W1[(size_t)k * M + (col - M)];
        else      v = W0[(size_t)k * M + col];
        tmp[e] = __float2half(v);
    }
    *(uint4*)(Wp + (size_t)idx * 8) = *(uint4*)tmp;
}

// MFMA dual GEMM: one wave per (16-row tile, col quarter); no LDS.
template<int NC, int K>
__global__ __launch_bounds__(256)
void gemm_mfma_kernel(const __half* __restrict__ A, const __half* __restrict__ Wp,
                      __half* __restrict__ Y0, __half* __restrict__ Y1, int n) {
    constexpr int KC = K / 32;
    constexpr int NT = NC / 16;
    constexpr int NTW = NT / 4;
    constexpr int M = NC / 2;
    int gw = (int)((blockIdx.x * 256 + threadIdx.x) >> 6);
    int lane = threadIdx.x & 63;
    int rt = gw >> 2;
    int wq = gw & 3;
    int row0 = rt * 16;
    if (row0 >= n) return;
    int arow = row0 + (lane & 15);
    int koff = (lane >> 4) * 8;
    half8_t af[KC];
    #pragma unroll
    for (int c = 0; c < KC; c++) {
        af[c] = (arow < n) ? *(const half8_t*)(A + (size_t)arow * K + c * 32 + koff)
                           : half8_t{0, 0, 0, 0, 0, 0, 0, 0};
    }
    #pragma unroll
    for (int t4 = 0; t4 < NTW; t4++) {
        int t = wq * NTW + t4;
        f32x4_t acc = {0.f, 0.f, 0.f, 0.f};
        #pragma unroll
        for (int c = 0; c < KC; c++) {
            half8_t bf = *(const half8_t*)(Wp + (((size_t)t * KC + c) * 64 + lane) * 8);
            acc = __builtin_amdgcn_mfma_f32_16x16x32_f16(af[c], bf, acc, 0, 0, 0);
        }
        int col = t * 16 + (lane & 15);
        #pragma unroll
        for (int r = 0; r < 4; r++) {
            int row = row0 + (lane >> 4) * 4 + r;
            if (row < n) {
                __half v = __float2half(acc[r]);
                if (col < M) Y0[(size_t)row * M + col] = v;
                else         Y1[(size_t)row * M + (col - M)] = v;
            }
        }
    }
}

// One group of GL=4*H lanes per NODE (lane owns 16 channels; whole row in
// group). Per-head logit reduce = quad DPP (heads align with quads).
// Depth-2 register pipeline on the src-row gathers.
// LS_MODE=false: out = relu(agg/d + bias) -> fp16 (h1).
// LS_MODE=true:  v = agg/d + bias -> log_softmax (quad reduce) -> fp32+fp16.
template<int H, bool LS_MODE>
__global__ __launch_bounds__(256)
void node_agg_kernel(const __half* __restrict__ xl, const __half* __restrict__ xr,
                     const int* __restrict__ rowptr, const int* __restrict__ srcs,
                     const float* __restrict__ att, const float* __restrict__ bias,
                     __half* __restrict__ outh, float* __restrict__ outf, int n) {
    constexpr int GL = 4 * H;          // lanes per group
    constexpr int HC = 64 * H;         // channels per row
    int g = (int)((blockIdx.x * blockDim.x + threadIdx.x) / GL);
    int lane = (int)(threadIdx.x % GL);
    if (g >= n) return;
    int node = g;
    int cb = lane * 16;

    const __half* xrp = xr + (size_t)node * HC + cb;
    uint4 ur0 = *(const uint4*)(xrp);
    uint4 ur1 = *(const uint4*)(xrp + 8);
    h2 r[8] = {bch2(ur0.x), bch2(ur0.y), bch2(ur0.z), bch2(ur0.w),
               bch2(ur1.x), bch2(ur1.y), bch2(ur1.z), bch2(ur1.w)};
    const float* ap = att + cb;
    h2 a[8];
    #pragma unroll
    for (int j = 0; j < 8; j++)
        a[j] = h2{(_Float16)ap[2 * j], (_Float16)ap[2 * j + 1]};
    const h2 k02 = {(_Float16)0.2f, (_Float16)0.2f};

    int start = rowptr[node], end = rowptr[node + 1];
    float d = 0.f;
    float acc[16];
    #pragma unroll
    for (int j = 0; j < 16; j++) acc[j] = 0.f;

    auto edge = [&](uint4 u0, uint4 u1) {
        h2 l[8] = {bch2(u0.x), bch2(u0.y), bch2(u0.z), bch2(u0.w),
                   bch2(u1.x), bch2(u1.y), bch2(u1.z), bch2(u1.w)};
        float pa = 0.f, pb = 0.f;
        #pragma unroll
        for (int j = 0; j < 4; j++) {
            h2 s = l[j] + r[j];
            s = __builtin_elementwise_max(s, s * k02);   // leaky_relu
            pa = __builtin_amdgcn_fdot2(s, a[j], pa, false);
        }
        #pragma unroll
        for (int j = 4; j < 8; j++) {
            h2 s = l[j] + r[j];
            s = __builtin_elementwise_max(s, s * k02);
            pb = __builtin_amdgcn_fdot2(s, a[j], pb, false);
        }
        float p = pa + pb;
        p += dpp_xor1(p);
        p += dpp_xor2(p);          // quad holds its head's logit
        float w = __expf(p);
        d += w;
        #pragma unroll
        for (int j = 0; j < 8; j++) {
            acc[2 * j]     += w * (float)l[j][0];
            acc[2 * j + 1] += w * (float)l[j][1];
        }
    };

    // depth-2 software pipeline (deg >= 1 guaranteed by self-loop)
    uint4 A0, A1, B0 = {}, B1 = {};
    {
        int s0 = srcs[start];
        const __half* p = xl + (size_t)s0 * HC + cb;
        A0 = *(const uint4*)p; A1 = *(const uint4*)(p + 8);
    }
    if (start + 1 < end) {
        int s1 = srcs[start + 1];
        const __half* p = xl + (size_t)s1 * HC + cb;
        B0 = *(const uint4*)p; B1 = *(const uint4*)(p + 8);
    }
    int k = start;
    for (; k + 2 <= end; k += 2) {
        uint4 x0 = A0, x1 = A1;
        if (k + 2 < end) {
            int s = srcs[k + 2];
            const __half* p = xl + (size_t)s * HC + cb;
            A0 = *(const uint4*)p; A1 = *(const uint4*)(p + 8);
        }
        edge(x0, x1);
        uint4 y0 = B0, y1 = B1;
        if (k + 3 < end) {
            int s = srcs[k + 3];
            const __half* p = xl + (size_t)s * HC + cb;
            B0 = *(const uint4*)p; B1 = *(const uint4*)(p + 8);
        }
        edge(y0, y1);
    }
    if (k < end) edge(A0, A1);     // odd remainder sits in A

    float inv = 1.f / (d + 1e-16f);
    const float* bp = bias + cb;
    if (!LS_MODE) {
        float o[16];
        #pragma unroll
        for (int j = 0; j < 16; j++) o[j] = fmaxf(acc[j] * inv + bp[j], 0.f);
        __half* op = outh + (size_t)node * HC + cb;
        uint4 w0, w1;
        __half2 t0 = __floats2half2_rn(o[0], o[1]),  t1 = __floats2half2_rn(o[2], o[3]);
        __half2 t2 = __floats2half2_rn(o[4], o[5]),  t3 = __floats2half2_rn(o[6], o[7]);
        __half2 t4 = __floats2half2_rn(o[8], o[9]),  t5 = __floats2half2_rn(o[10], o[11]);
        __half2 t6 = __floats2half2_rn(o[12], o[13]), t7 = __floats2half2_rn(o[14], o[15]);
        w0.x = *(unsigned int*)&t0; w0.y = *(unsigned int*)&t1;
        w0.z = *(unsigned int*)&t2; w0.w = *(unsigned int*)&t3;
        w1.x = *(unsigned int*)&t4; w1.y = *(unsigned int*)&t5;
        w1.z = *(unsigned int*)&t6; w1.w = *(unsigned int*)&t7;
        *(uint4*)(op) = w0;
        *(uint4*)(op + 8) = w1;
    } else {
        // fused log_softmax over the row (held across the quad)
        float v[16];
        #pragma unroll
        for (int j = 0; j < 16; j++) v[j] = acc[j] * inv + bp[j];
        float m = v[0];
        #pragma unroll
        for (int j = 1; j < 16; j++) m = fmaxf(m, v[j]);
        m = fmaxf(m, dpp_xor1(m));
        m = fmaxf(m, dpp_xor2(m));
        float s = 0.f;
        #pragma unroll
        for (int j = 0; j < 16; j++) s += __expf(v[j] - m);
        s += dpp_xor1(s);
        s += dpp_xor2(s);
        float lg = __logf(s);
        float ls[16];
        #pragma unroll
        for (int j = 0; j < 16; j++) ls[j] = v[j] - m - lg;
        float* of = outf + (size_t)node * HC + cb;
        #pragma unroll
        for (int q = 0; q < 4; q++)
            *(float4*)(of + q * 4) = make_float4(ls[q * 4], ls[q * 4 + 1], ls[q * 4 + 2], ls[q * 4 + 3]);
        __half* op = outh + (size_t)node * HC + cb;
        uint4 w0, w1;
        __half2 t0 = __floats2half2_rn(ls[0], ls[1]),  t1 = __floats2half2_rn(ls[2], ls[3]);
        __half2 t2 = __floats2half2_rn(ls[4], ls[5]),  t3 = __floats2half2_rn(ls[6], ls[7]);
        __half2 t4 = __floats2half2_rn(ls[8], ls[9]),  t5 = __floats2half2_rn(ls[10], ls[11]);
        __half2 t6 = __floats2half2_rn(ls[12], ls[13]), t7 = __floats2half2_rn(ls[14], ls[15]);
        w0.x = *(unsigned int*)&t0; w0.y = *(unsigned int*)&t1;
        w0.z = *(unsigned int*)&t2; w0.w = *(unsigned int*)&t3;
        w1.x = *(unsigned int*)&t4; w1.y = *(unsigned int*)&t5;
        w1.z = *(unsigned int*)&t6; w1.w = *(unsigned int*)&t7;
        *(uint4*)(op) = w0;
        *(uint4*)(op + 8) = w1;
    }
}

// Fused rule-net: T = relu(LS@We1+be1) (MFMA via LDS fp16 transpose),
// G = T@We2+be2, out = ls + sigmoid(G).
__global__ __launch_bounds__(256)
void gate_kernel(const float* __restrict__ lsf, const __half* __restrict__ lsh,
                 const __half* __restrict__ We1p, const float* __restrict__ be1,
                 const __half* __restrict__ We2p, const float* __restrict__ be2,
                 float* __restrict__ out, int n) {
    __shared__ _Float16 tls[4][16][64];
    int wid = threadIdx.x >> 6, lane = threadIdx.x & 63;
    int row0 = (blockIdx.x * 4 + wid) * 16;
    if (row0 >= n) return;
    int arow = row0 + (lane & 15);
    int koff = (lane >> 4) * 8;
    int colw = lane & 15;
    int rbase = (lane >> 4) * 4;

    half8_t af0 = (arow < n) ? *(const half8_t*)(lsh + (size_t)arow * 64 + koff)
                             : half8_t{0, 0, 0, 0, 0, 0, 0, 0};
    half8_t af1 = (arow < n) ? *(const half8_t*)(lsh + (size_t)arow * 64 + 32 + koff)
                             : half8_t{0, 0, 0, 0, 0, 0, 0, 0};
    #pragma unroll
    for (int t = 0; t < 4; t++) {
        f32x4_t acc = {0.f, 0.f, 0.f, 0.f};
        half8_t b0 = *(const half8_t*)(We1p + (((size_t)t * 2 + 0) * 64 + lane) * 8);
        half8_t b1 = *(const half8_t*)(We1p + (((size_t)t * 2 + 1) * 64 + lane) * 8);
        acc = __builtin_amdgcn_mfma_f32_16x16x32_f16(af0, b0, acc, 0, 0, 0);
        acc = __builtin_amdgcn_mfma_f32_16x16x32_f16(af1, b1, acc, 0, 0, 0);
        float bv = be1[t * 16 + colw];
        #pragma unroll
        for (int r = 0; r < 4; r++)
            tls[wid][rbase + r][t * 16 + colw] = (_Float16)fmaxf(acc[r] + bv, 0.f);
    }
    half8_t tf0 = *(const half8_t*)&tls[wid][lane & 15][koff];
    half8_t tf1 = *(const half8_t*)&tls[wid][lane & 15][32 + koff];
    #pragma unroll
    for (int t = 0; t < 4; t++) {
        f32x4_t acc = {0.f, 0.f, 0.f, 0.f};
        half8_t b0 = *(const half8_t*)(We2p + (((size_t)t * 2 + 0) * 64 + lane) * 8);
        half8_t b1 = *(const half8_t*)(We2p + (((size_t)t * 2 + 1) * 64 + lane) * 8);
        acc = __builtin_amdgcn_mfma_f32_16x16x32_f16(tf0, b0, acc, 0, 0, 0);
        acc = __builtin_amdgcn_mfma_f32_16x16x32_f16(tf1, b1, acc, 0, 0, 0);
        int col = t * 16 + colw;
        float bv = be2[col];
        #pragma unroll
        for (int r = 0; r < 4; r++) {
            int row = row0 + rbase + r;
            if (row < n) {
                float g = 1.f / (1.f + __expf(-(acc[r] + bv)));
                out[(size_t)row * 64 + col] = lsf[(size_t)row * 64 + col] + g;
            }
        }
    }
}

extern "C" void kernel_launch(void* const* d_in, const int* in_sizes, int n_in,
                              void* d_out, int out_size, void* d_ws, size_t ws_size,
                              hipStream_t stream) {
    const float* x    = (const float*)d_in[0];
    const int*   ei   = (const int*)d_in[1];
    const float* Wl1  = (const float*)d_in[2];
    const float* Wr1  = (const float*)d_in[3];
    const float* att1 = (const float*)d_in[4];
    const float* b1   = (const float*)d_in[5];
    const float* Wl2  = (const float*)d_in[6];
    const float* Wr2  = (const float*)d_in[7];
    const float* att2 = (const float*)d_in[8];
    const float* b2   = (const float*)d_in[9];
    const float* We1  = (const float*)d_in[10];
    const float* be1  = (const float*)d_in[11];
    const float* We2  = (const float*)d_in[12];
    const float* be2  = (const float*)d_in[13];
    float* out = (float*)d_out;

    const int n  = in_sizes[0] / 128;
    const int E  = in_sizes[1] / 2;
    const int ET = E + n;
    const int nchunks = (n + 1023) / 1024;
    const int nb = (n + BKT_W - 1) / BKT_W;

    float* ws = (float*)d_ws;
    size_t o = 0;
    __half* xl1 = (__half*)(ws + o); o += (size_t)n * 64;   // [n,128] fp16
    __half* xr1 = (__half*)(ws + o); o += (size_t)n * 64;   // [n,128] fp16
    __half* xh  = (__half*)(ws + o); o += (size_t)n * 64;   // x as fp16 [n,128]
    __half* h1h = (__half*)(ws + o); o += (size_t)n * 64;   // h1 fp16 [n,128]
    float*  v2  = ws + o;            o += (size_t)n * 64;   // ls fp32 [n,64]
    __half* lsh = (__half*)(ws + o); o += (size_t)n * 32;   // ls fp16 [n,64]
    __half* Wp1 = (__half*)(ws + o); o += 16384;
    __half* Wp2 = (__half*)(ws + o); o += 8192;
    __half* We1p = (__half*)(ws + o); o += 2048;
    __half* We2p = (__half*)(ws + o); o += 2048;
    int* rowptr   = (int*)(ws + o); o += (size_t)(n + 1);
    int* degP     = (int*)(ws + o); o += (size_t)n * CSTR;  // padded deg counters
    int* srcs     = (int*)(ws + o); o += (size_t)ET;
    int* partials = (int*)(ws + o); o += 1024;
    uint2* pairs  = (uint2*)(ws + o); o += (size_t)E * 2;   // bucketed (src,dst)
    int* bcur     = (int*)(ws + o); o += 128 * CSTR;        // bucket cursors
    __half* xl2 = xl1;                     // [n,64] fp16 (reuses dead xl1 region)
    __half* xr2 = xl1 + (size_t)n * 64;
    float* lsf = v2;

    const int BS = 256;
    auto blocks = [](long long t, int bs) { return (int)((t + bs - 1) / bs); };

    // ---- CSR build (by dst), self-loops via deg init = 1 ----
    fill_strided_kernel<<<blocks(n, BS), BS, 0, stream>>>(degP, 1, n);
    hist_kernel<<<blocks(E, BS), BS, 0, stream>>>(ei, degP, E);
    scan_block_kernel<<<nchunks, 1024, 0, stream>>>(degP, rowptr, partials, n);
    scan_partials_kernel<<<1, 1024, 0, stream>>>(partials, nchunks);
    scan_apply_kernel<<<nchunks, 1024, 0, stream>>>(rowptr, partials, n);
    bucket_seed_kernel<<<1, 128, 0, stream>>>(rowptr, bcur, nb);
    bucket_pass_kernel<<<blocks(E, 1024 * PA_EPT), 1024, 0, stream>>>(ei, E, bcur, pairs, nb);
    bucket_scatter_kernel<<<nb, 1024, 0, stream>>>(pairs, rowptr, srcs, n);

    // ---- one-time conversions / packs ----
    f2h_kernel<<<blocks((long long)n * 32, BS), BS, 0, stream>>>(x, xh, (long long)n * 32);
    pack_w_kernel<256, 128, true><<<16, 256, 0, stream>>>(Wl1, Wr1, Wp1);
    pack_w_kernel<128, 128, true><<<8, 256, 0, stream>>>(Wl2, Wr2, Wp2);
    pack_w_kernel<64, 64, false><<<2, 256, 0, stream>>>(We1, nullptr, We1p);
    pack_w_kernel<64, 64, false><<<2, 256, 0, stream>>>(We2, nullptr, We2p);

    // ---- layer 1 ----
    const int rt = (n + 15) / 16;          // row tiles
    gemm_mfma_kernel<256, 128><<<rt, 256, 0, stream>>>(xh, Wp1, xl1, xr1, n);
    node_agg_kernel<2, false><<<blocks((long long)n * 8, BS), BS, 0, stream>>>(
        xl1, xr1, rowptr, srcs, att1, b1, h1h, nullptr, n);

    // ---- layer 2 (log_softmax fused into agg) ----
    gemm_mfma_kernel<128, 128><<<rt, 256, 0, stream>>>(h1h, Wp2, xl2, xr2, n);
    node_agg_kernel<1, true><<<blocks((long long)n * 4, BS), BS, 0, stream>>>(
        xl2, xr2, rowptr, srcs, att2, b2, lsh, v2, n);

    // ---- finalize: fused MFMA rule-net ----
    gate_kernel<<<(n + 63) / 64, BS, 0, stream>>>(lsf, lsh, We1p, be1, We2p, be2, out, n);
}